// Round 8
// baseline (346.759 us; speedup 1.0000x reference)
//
#include <hip/hip_runtime.h>
#include <hip/hip_bf16.h>

#define N_NODES 50000
#define N_EDGES 800000
#define HIDDEN  128
#define OUT_F   10
#define N_GRAPHS 128
#define EPS 1e-5f

#define NB   391                    // ceil(50000/128) buckets of 128 nodes
#define BCAP 3072                   // bucket capacity (mean 2048)
#define SLICE (N_EDGES / 256)       // 3125 edges per partition block

#define CASTX_BLOCKS 12500          // N_NODES*64 float2 / 256
#define CASTW_BLOCKS 256            // 65536 / 256
#define POOLZ_BLOCKS 64             // 16384 / 256

using short8 = __attribute__((ext_vector_type(8))) short;
using f32x4  = __attribute__((ext_vector_type(4))) float;

// ---------------------------------------------------------------------------
// fused: cast x -> bf16, build Wt (transposed [W_rel;W_root]) bf16,
// zero cursor + pooled. One launch replaces 4.
__global__ void cast_zero_kernel(const float* __restrict__ x, __hip_bfloat16* __restrict__ xb,
                                 const float* __restrict__ Wrel, const float* __restrict__ Wroot,
                                 __hip_bfloat16* __restrict__ Wt,
                                 int* __restrict__ cursor, float* __restrict__ pooled) {
    const int b = blockIdx.x, tid = threadIdx.x;
    if (b < CASTX_BLOCKS) {
        int i = b * 256 + tid;                       // one float2 per thread
        float2 v = ((const float2*)x)[i];
        __hip_bfloat162 o;
        o.x = __float2bfloat16(v.x);
        o.y = __float2bfloat16(v.y);
        ((__hip_bfloat162*)xb)[i] = o;
    } else if (b < CASTX_BLOCKS + CASTW_BLOCKS) {
        int idx = (b - CASTX_BLOCKS) * 256 + tid;    // 2*128*256 = 65536
        int l = idx >> 15;
        int rem = idx & 32767;
        int n = rem >> 8;
        int k = rem & 255;
        float v = (k < HIDDEN) ? Wrel[l * HIDDEN * HIDDEN + k * HIDDEN + n]
                               : Wroot[l * HIDDEN * HIDDEN + (k - HIDDEN) * HIDDEN + n];
        Wt[idx] = __float2bfloat16(v);
    } else if (b < CASTX_BLOCKS + CASTW_BLOCKS + POOLZ_BLOCKS) {
        int i = (b - CASTX_BLOCKS - CASTW_BLOCKS) * 256 + tid;  // 16384
        pooled[i] = 0.f;
    } else {
        for (int i = tid; i < NB; i += 256) cursor[i] = 0;
    }
}

// ---------------------------------------------------------------------------
// CSR build via bucket partition (all scatter confined to LDS).
__global__ __launch_bounds__(256) void part_kernel(
        const int* __restrict__ src, const int* __restrict__ dst,
        int* __restrict__ cursor, int* __restrict__ ebuf) {
    __shared__ int s_pk[SLICE];
    __shared__ unsigned short s_bk[SLICE];
    __shared__ int hist[NB], base[NB];
    const int tid = threadIdx.x;
    const int e0 = blockIdx.x * SLICE;
    for (int i = tid; i < NB; i += 256) hist[i] = 0;
    __syncthreads();
    for (int i = tid; i < SLICE; i += 256) {
        int s = src[e0 + i], d = dst[e0 + i];
        int b = d >> 7;
        s_pk[i] = s | ((d & 127) << 16);
        s_bk[i] = (unsigned short)b;
        atomicAdd(&hist[b], 1);
    }
    __syncthreads();
    for (int i = tid; i < NB; i += 256) {
        int h = hist[i];
        base[i] = h ? atomicAdd(&cursor[i], h) : 0;
        hist[i] = 0;                         // reuse as local cursor
    }
    __syncthreads();
    for (int i = tid; i < SLICE; i += 256) {
        int b = s_bk[i];
        int off = base[b] + atomicAdd(&hist[b], 1);
        if (off < BCAP) ebuf[b * BCAP + off] = s_pk[i];
    }
}

// per-bucket local counting sort -> deg/inv_deg/row_ptr + coalesced csr write.
// bucket base offset computed inline (sum of cursor[0..b)) - no bscan kernel.
__global__ __launch_bounds__(256) void fillb_kernel(
        const int* __restrict__ cursor, const int* __restrict__ ebuf,
        int* __restrict__ row_ptr, float* __restrict__ inv_deg,
        int* __restrict__ csr_src) {
    __shared__ int lcsr[BCAP];
    __shared__ int hist[128], lofs[128];
    __shared__ int wtot[2];
    __shared__ int sred[4];
    __shared__ int sbase;
    const int b = blockIdx.x;
    const int tid = threadIdx.x;

    // base = exclusive prefix sum of cursor at b
    int partial = 0;
    for (int i = tid; i < b; i += 256) partial += cursor[i];
    #pragma unroll
    for (int off = 1; off < 64; off <<= 1) partial += __shfl_xor(partial, off, 64);
    if ((tid & 63) == 0) sred[tid >> 6] = partial;
    if (tid < 128) hist[tid] = 0;
    __syncthreads();
    if (tid == 0) sbase = sred[0] + sred[1] + sred[2] + sred[3];
    __syncthreads();
    const int base = sbase;

    int cnt = cursor[b]; if (cnt > BCAP) cnt = BCAP;
    const int* eb = ebuf + b * BCAP;

    for (int i = tid; i < cnt; i += 256) atomicAdd(&hist[eb[i] >> 16], 1);
    __syncthreads();
    if (tid < 128) {
        int lane = tid & 63;
        int v = hist[tid];
        int inc = v;
        #pragma unroll
        for (int off = 1; off < 64; off <<= 1) {
            int t = __shfl_up(inc, off, 64);
            if (lane >= off) inc += t;
        }
        lofs[tid] = inc - v;
        if (lane == 63) wtot[tid >> 6] = inc;
    }
    __syncthreads();
    if (tid >= 64 && tid < 128) lofs[tid] += wtot[0];
    __syncthreads();
    if (tid < 128) {
        int node = b * 128 + tid;
        if (node < N_NODES) {
            row_ptr[node] = base + lofs[tid];
            int d = hist[tid];
            inv_deg[node] = (d > 0) ? (1.0f / (float)d) : 0.0f;
        }
        hist[tid] = lofs[tid];               // running local cursor
    }
    if (b == 0 && tid == 0) row_ptr[N_NODES] = N_EDGES;
    __syncthreads();
    for (int i = tid; i < cnt; i += 256) {
        int pk = eb[i];
        int p = atomicAdd(&hist[pk >> 16], 1);
        lcsr[p] = pk & 0xFFFF;
    }
    __syncthreads();
    for (int i = tid; i < cnt; i += 256) csr_src[base + i] = lcsr[i];
}

// ---------------------------------------------------------------------------
// FUSED: mean-aggregate (gather) directly into the LDS A-tile, then
// MFMA GEMM + bias + LayerNorm + ReLU. bf16 in/out, fp32 accum.
// Tile: 64 nodes x 128 cols, K=256 ([agg|x]). Wave w aggregates nodes
// base+16w..+15 (2-edge/512B gathers, R6 scheme) and owns cols 32w..32w+31.
#define GM 64
__global__ __launch_bounds__(256) void gemm_fused_kernel(
        const __hip_bfloat16* __restrict__ xin, __hip_bfloat16* __restrict__ xout,
        const int* __restrict__ row_ptr, const int* __restrict__ csr_src,
        const float* __restrict__ inv_deg,
        const __hip_bfloat16* __restrict__ Wt,   // [128][256] bf16 (n-major)
        const float* __restrict__ brel, const float* __restrict__ gamma,
        const float* __restrict__ beta) {
    __shared__ __align__(16) short sA[GM * 264];   // 64 rows x 256 k, +8 pad
    __shared__ float red[GM][4][2];

    const int tid  = threadIdx.x;
    const int w    = tid >> 6;
    const int lane = tid & 63;
    const int q    = lane >> 4;
    const int l15  = lane & 15;
    const int base = blockIdx.x * GM;

    // stage x half (k 128..255): 64 rows x 16 chunks of 8 bf16 = 1024 -> 4 iters
    for (int it = 0; it < 4; ++it) {
        int c = it * 256 + tid;
        int row = c >> 4, cc = c & 15;
        int node = base + row;
        short8 v = {0,0,0,0,0,0,0,0};
        if (node < N_NODES)
            v = *(const short8*)((const short*)xin + (size_t)node * HIDDEN + cc * 8);
        *(short8*)&sA[row * 264 + 128 + cc * 8] = v;
    }

    // aggregate half (k 0..127): wave w does 16 nodes, 2-edge/512B gathers
    const int half = lane >> 5;
    const int l32  = lane & 31;
    for (int nl = 0; nl < 16; ++nl) {
        const int rowl = w * 16 + nl;
        const int node = base + rowl;
        float s0 = 0.f, s1 = 0.f, s2 = 0.f, s3 = 0.f;
        if (node < N_NODES) {
            const int beg = row_ptr[node], end = row_ptr[node + 1];
            float a[4][4];
            #pragma unroll
            for (int u = 0; u < 4; ++u)
                #pragma unroll
                for (int k = 0; k < 4; ++k) a[u][k] = 0.f;
            for (int c = beg; c < end; c += 64) {
                int ei = c + lane;
                int sidx = (ei < end) ? csr_src[ei] : 0;
                int nedge = end - c; if (nedge > 64) nedge = 64;
                int npair = nedge >> 1;
                int j = 0;
                for (; j + 4 <= npair; j += 4) {
                    #pragma unroll
                    for (int u = 0; u < 4; ++u) {
                        int sj = __shfl(sidx, 2 * (j + u) + half, 64);
                        float2 v = ((const float2*)(xin + (size_t)sj * HIDDEN))[l32];
                        __hip_bfloat162 b0 = *(__hip_bfloat162*)&v.x;
                        __hip_bfloat162 b1 = *(__hip_bfloat162*)&v.y;
                        a[u][0] += __bfloat162float(b0.x);
                        a[u][1] += __bfloat162float(b0.y);
                        a[u][2] += __bfloat162float(b1.x);
                        a[u][3] += __bfloat162float(b1.y);
                    }
                }
                for (; j < npair; ++j) {
                    int sj = __shfl(sidx, 2 * j + half, 64);
                    float2 v = ((const float2*)(xin + (size_t)sj * HIDDEN))[l32];
                    __hip_bfloat162 b0 = *(__hip_bfloat162*)&v.x;
                    __hip_bfloat162 b1 = *(__hip_bfloat162*)&v.y;
                    a[0][0] += __bfloat162float(b0.x);
                    a[0][1] += __bfloat162float(b0.y);
                    a[0][2] += __bfloat162float(b1.x);
                    a[0][3] += __bfloat162float(b1.y);
                }
                if (nedge & 1) {
                    int sj = __shfl(sidx, nedge - 1, 64);
                    if (half == 0) {
                        float2 v = ((const float2*)(xin + (size_t)sj * HIDDEN))[l32];
                        __hip_bfloat162 b0 = *(__hip_bfloat162*)&v.x;
                        __hip_bfloat162 b1 = *(__hip_bfloat162*)&v.y;
                        a[0][0] += __bfloat162float(b0.x);
                        a[0][1] += __bfloat162float(b0.y);
                        a[0][2] += __bfloat162float(b1.x);
                        a[0][3] += __bfloat162float(b1.y);
                    }
                }
            }
            s0 = a[0][0] + a[1][0] + a[2][0] + a[3][0];
            s1 = a[0][1] + a[1][1] + a[2][1] + a[3][1];
            s2 = a[0][2] + a[1][2] + a[2][2] + a[3][2];
            s3 = a[0][3] + a[1][3] + a[2][3] + a[3][3];
            s0 += __shfl_xor(s0, 32, 64);
            s1 += __shfl_xor(s1, 32, 64);
            s2 += __shfl_xor(s2, 32, 64);
            s3 += __shfl_xor(s3, 32, 64);
            float wd = inv_deg[node];
            s0 *= wd; s1 *= wd; s2 *= wd; s3 *= wd;
        }
        if (half == 0) {
            union { __hip_bfloat162 h[2]; uint2 u; } o;
            o.h[0].x = __float2bfloat16(s0);
            o.h[0].y = __float2bfloat16(s1);
            o.h[1].x = __float2bfloat16(s2);
            o.h[1].y = __float2bfloat16(s3);
            *(uint2*)&sA[rowl * 264 + l32 * 4] = o.u;   // feats 4*l32..+3
        }
    }

    // B fragments (L2-hot): 2 ntiles x 8 ksteps
    short8 breg[2][8];
    #pragma unroll
    for (int nt = 0; nt < 2; ++nt) {
        int col = 32 * w + nt * 16 + l15;
        const short* wp = (const short*)Wt + (size_t)col * 256;
        #pragma unroll
        for (int ks = 0; ks < 8; ++ks)
            breg[nt][ks] = *(const short8*)(wp + ks * 32 + q * 8);
    }
    __syncthreads();

    f32x4 acc[4][2];
    #pragma unroll
    for (int mt = 0; mt < 4; ++mt)
        #pragma unroll
        for (int nt = 0; nt < 2; ++nt)
            acc[mt][nt] = (f32x4){0.f, 0.f, 0.f, 0.f};

    #pragma unroll
    for (int ks = 0; ks < 8; ++ks) {
        short8 a[4];
        #pragma unroll
        for (int mt = 0; mt < 4; ++mt)
            a[mt] = *(short8*)&sA[(mt * 16 + l15) * 264 + ks * 32 + q * 8];
        #pragma unroll
        for (int mt = 0; mt < 4; ++mt) {
            acc[mt][0] = __builtin_amdgcn_mfma_f32_16x16x32_bf16(a[mt], breg[0][ks], acc[mt][0], 0, 0, 0);
            acc[mt][1] = __builtin_amdgcn_mfma_f32_16x16x32_bf16(a[mt], breg[1][ks], acc[mt][1], 0, 0, 0);
        }
    }

    const int col0 = 32 * w + l15, col1 = col0 + 16;
    const float b0 = brel[col0], b1 = brel[col1];
    #pragma unroll
    for (int mt = 0; mt < 4; ++mt) {
        #pragma unroll
        for (int r = 0; r < 4; ++r) {
            acc[mt][0][r] += b0;
            acc[mt][1][r] += b1;
            float s  = acc[mt][0][r] + acc[mt][1][r];
            float s2 = acc[mt][0][r] * acc[mt][0][r] + acc[mt][1][r] * acc[mt][1][r];
            #pragma unroll
            for (int off = 1; off < 16; off <<= 1) {
                s  += __shfl_xor(s,  off, 64);
                s2 += __shfl_xor(s2, off, 64);
            }
            if (l15 == 0) {
                red[mt * 16 + q * 4 + r][w][0] = s;
                red[mt * 16 + q * 4 + r][w][1] = s2;
            }
        }
    }
    __syncthreads();

    const float g0 = gamma[col0], g1 = gamma[col1];
    const float e0 = beta[col0],  e1 = beta[col1];
    #pragma unroll
    for (int mt = 0; mt < 4; ++mt) {
        #pragma unroll
        for (int r = 0; r < 4; ++r) {
            int row = mt * 16 + q * 4 + r;
            float tot  = red[row][0][0] + red[row][1][0] + red[row][2][0] + red[row][3][0];
            float tot2 = red[row][0][1] + red[row][1][1] + red[row][2][1] + red[row][3][1];
            float mu  = tot * (1.0f / HIDDEN);
            float var = tot2 * (1.0f / HIDDEN) - mu * mu;
            float rs  = rsqrtf(var + EPS);
            int node = base + row;
            if (node < N_NODES) {
                float v0 = fmaxf(g0 * (acc[mt][0][r] - mu) * rs + e0, 0.f);
                float v1 = fmaxf(g1 * (acc[mt][1][r] - mu) * rs + e1, 0.f);
                xout[(size_t)node * HIDDEN + col0] = __float2bfloat16(v0);
                xout[(size_t)node * HIDDEN + col1] = __float2bfloat16(v1);
            }
        }
    }
}

// ---------------------------------------------------------------------------
// segmented mean-pool over SORTED batch (bf16 in, fp32 atomics out)
#define POOL_WAVES 1024
#define POOL_CHUNK ((N_NODES + POOL_WAVES - 1) / POOL_WAVES)  // 49
__global__ void pool_kernel(const __hip_bfloat16* __restrict__ x, const int* __restrict__ batch,
                            float* __restrict__ pooled) {
    int wave = blockIdx.x * (blockDim.x >> 6) + (threadIdx.x >> 6);
    int lane = threadIdx.x & 63;
    int n0 = wave * POOL_CHUNK;
    int n1 = n0 + POOL_CHUNK; if (n1 > N_NODES) n1 = N_NODES;
    if (n0 >= N_NODES) return;
    const __hip_bfloat162* xf = (const __hip_bfloat162*)x;
    int cur_g = batch[n0];
    float sx = 0.f, sy = 0.f;
    for (int n = n0; n < n1; ++n) {
        int g = batch[n];
        if (g != cur_g) {
            atomicAdd(&pooled[cur_g * HIDDEN + lane * 2 + 0], sx);
            atomicAdd(&pooled[cur_g * HIDDEN + lane * 2 + 1], sy);
            sx = 0.f; sy = 0.f; cur_g = g;
        }
        __hip_bfloat162 v = xf[(size_t)n * 64 + lane];
        sx += __bfloat162float(v.x);
        sy += __bfloat162float(v.y);
    }
    atomicAdd(&pooled[cur_g * HIDDEN + lane * 2 + 0], sx);
    atomicAdd(&pooled[cur_g * HIDDEN + lane * 2 + 1], sy);
}

// head (derives per-graph counts from the sorted batch array)
__global__ void out_kernel(const float* __restrict__ pooled, const int* __restrict__ batch,
                           const float* __restrict__ Wc, const float* __restrict__ bc,
                           float* __restrict__ out) {
    int idx = blockIdx.x * blockDim.x + threadIdx.x;
    if (idx >= N_GRAPHS * OUT_F) return;
    int g = idx / OUT_F, o = idx % OUT_F;
    int lo = 0, hi = N_NODES;
    while (lo < hi) { int m = (lo + hi) >> 1; if (batch[m] < g) lo = m + 1; else hi = m; }
    int b0 = lo;
    lo = 0; hi = N_NODES;
    while (lo < hi) { int m = (lo + hi) >> 1; if (batch[m] < g + 1) lo = m + 1; else hi = m; }
    float cntf = (float)(lo - b0);
    float inv = 1.0f / fmaxf(cntf, 1.0f);
    float s = 0.f;
    for (int f = 0; f < HIDDEN; ++f)
        s += pooled[g * HIDDEN + f] * Wc[f * OUT_F + o];
    out[idx] = s * inv + bc[o];
}

// ---------------------------------------------------------------------------
static inline size_t align256(size_t v) { return (v + 255) & ~(size_t)255; }

extern "C" void kernel_launch(void* const* d_in, const int* in_sizes, int n_in,
                              void* d_out, int out_size, void* d_ws, size_t ws_size,
                              hipStream_t stream) {
    const float* x      = (const float*)d_in[0];
    const int*   eidx   = (const int*)d_in[1];
    const int*   batch  = (const int*)d_in[2];
    const float* W_rel  = (const float*)d_in[3];
    const float* b_rel  = (const float*)d_in[4];
    const float* W_root = (const float*)d_in[5];
    const float* gamma  = (const float*)d_in[6];
    const float* beta   = (const float*)d_in[7];
    const float* Wc     = (const float*)d_in[8];
    const float* bc     = (const float*)d_in[9];
    float* out = (float*)d_out;

    const int* src = eidx;
    const int* dst = eidx + N_EDGES;

    char* ws = (char*)d_ws;
    size_t off = 0;
    int*   row_ptr  = (int*)(ws + off);  off = align256(off + sizeof(int) * (N_NODES + 1));
    int*   csr_src  = (int*)(ws + off);  off = align256(off + sizeof(int) * N_EDGES);
    float* inv_deg  = (float*)(ws + off); off = align256(off + sizeof(float) * N_NODES);
    int*   cursor   = (int*)(ws + off);  off = align256(off + sizeof(int) * NB);
    int*   ebuf     = (int*)(ws + off);  off = align256(off + sizeof(int) * (size_t)NB * BCAP);
    __hip_bfloat16* x0b = (__hip_bfloat16*)(ws + off); off = align256(off + 2 * (size_t)N_NODES * HIDDEN);
    __hip_bfloat16* x1b = (__hip_bfloat16*)(ws + off); off = align256(off + 2 * (size_t)N_NODES * HIDDEN);
    __hip_bfloat16* x2b = (__hip_bfloat16*)(ws + off); off = align256(off + 2 * (size_t)N_NODES * HIDDEN);
    __hip_bfloat16* Wt  = (__hip_bfloat16*)(ws + off); off = align256(off + 2 * (size_t)2 * HIDDEN * 256);
    float* pooled   = (float*)(ws + off); off = align256(off + sizeof(float) * N_GRAPHS * HIDDEN);

    // casts + zero-init (cursor, pooled) in one launch
    cast_zero_kernel<<<CASTX_BLOCKS + CASTW_BLOCKS + POOLZ_BLOCKS + 1, 256, 0, stream>>>(
        x, x0b, W_rel, W_root, Wt, cursor, pooled);

    // CSR build via bucket partition (once; reused by both layers)
    part_kernel <<<256, 256, 0, stream>>>(src, dst, cursor, ebuf);
    fillb_kernel<<<NB, 256, 0, stream>>>(cursor, ebuf, row_ptr, inv_deg, csr_src);

    const int gemm_blocks = (N_NODES + GM - 1) / GM;   // 782

    // layer 0: gather+GEMM+LN+ReLU fused (x0b -> x1b)
    gemm_fused_kernel<<<gemm_blocks, 256, 0, stream>>>(
        x0b, x1b, row_ptr, csr_src, inv_deg, Wt, b_rel, gamma, beta);
    // layer 1: (x1b -> x2b; fresh buffer since blocks gather others' rows)
    gemm_fused_kernel<<<gemm_blocks, 256, 0, stream>>>(
        x1b, x2b, row_ptr, csr_src, inv_deg, Wt + 2 * HIDDEN * 256 / 2,
        b_rel + HIDDEN, gamma + HIDDEN, beta + HIDDEN);

    // pooling + head
    pool_kernel<<<POOL_WAVES / 4, 256, 0, stream>>>(x2b, batch, pooled);
    out_kernel<<<(N_GRAPHS * OUT_F + 255) / 256, 256, 0, stream>>>(pooled, batch, Wc, bc, out);
}

// Round 9
// 229.907 us; speedup vs baseline: 1.5083x; 1.5083x over previous
//
#include <hip/hip_runtime.h>
#include <hip/hip_bf16.h>

#define N_NODES 50000
#define N_EDGES 800000
#define HIDDEN  128
#define OUT_F   10
#define N_GRAPHS 128
#define EPS 1e-5f

#define NB   391                    // ceil(50000/128) buckets of 128 nodes
#define BCAP 3072                   // bucket capacity (mean 2048)
#define SLICE (N_EDGES / 256)       // 3125 edges per partition block

#define CASTX_BLOCKS 12500          // N_NODES*64 float2 / 256
#define CASTW_BLOCKS 256            // 65536 / 256
#define POOLZ_BLOCKS 64             // 16384 / 256

using short8 = __attribute__((ext_vector_type(8))) short;
using f32x4  = __attribute__((ext_vector_type(4))) float;

// ---------------------------------------------------------------------------
// fused: cast x -> bf16, build Wt (transposed [W_rel;W_root]) bf16,
// zero cursor + pooled. One launch replaces 4.
__global__ void cast_zero_kernel(const float* __restrict__ x, __hip_bfloat16* __restrict__ xb,
                                 const float* __restrict__ Wrel, const float* __restrict__ Wroot,
                                 __hip_bfloat16* __restrict__ Wt,
                                 int* __restrict__ cursor, float* __restrict__ pooled) {
    const int b = blockIdx.x, tid = threadIdx.x;
    if (b < CASTX_BLOCKS) {
        int i = b * 256 + tid;                       // one float2 per thread
        float2 v = ((const float2*)x)[i];
        __hip_bfloat162 o;
        o.x = __float2bfloat16(v.x);
        o.y = __float2bfloat16(v.y);
        ((__hip_bfloat162*)xb)[i] = o;
    } else if (b < CASTX_BLOCKS + CASTW_BLOCKS) {
        int idx = (b - CASTX_BLOCKS) * 256 + tid;    // 2*128*256 = 65536
        int l = idx >> 15;
        int rem = idx & 32767;
        int n = rem >> 8;
        int k = rem & 255;
        float v = (k < HIDDEN) ? Wrel[l * HIDDEN * HIDDEN + k * HIDDEN + n]
                               : Wroot[l * HIDDEN * HIDDEN + (k - HIDDEN) * HIDDEN + n];
        Wt[idx] = __float2bfloat16(v);
    } else if (b < CASTX_BLOCKS + CASTW_BLOCKS + POOLZ_BLOCKS) {
        int i = (b - CASTX_BLOCKS - CASTW_BLOCKS) * 256 + tid;  // 16384
        pooled[i] = 0.f;
    } else {
        for (int i = tid; i < NB; i += 256) cursor[i] = 0;
    }
}

// ---------------------------------------------------------------------------
// CSR build via bucket partition (all scatter confined to LDS).
__global__ __launch_bounds__(256) void part_kernel(
        const int* __restrict__ src, const int* __restrict__ dst,
        int* __restrict__ cursor, int* __restrict__ ebuf) {
    __shared__ int s_pk[SLICE];
    __shared__ unsigned short s_bk[SLICE];
    __shared__ int hist[NB], base[NB];
    const int tid = threadIdx.x;
    const int e0 = blockIdx.x * SLICE;
    for (int i = tid; i < NB; i += 256) hist[i] = 0;
    __syncthreads();
    for (int i = tid; i < SLICE; i += 256) {
        int s = src[e0 + i], d = dst[e0 + i];
        int b = d >> 7;
        s_pk[i] = s | ((d & 127) << 16);
        s_bk[i] = (unsigned short)b;
        atomicAdd(&hist[b], 1);
    }
    __syncthreads();
    for (int i = tid; i < NB; i += 256) {
        int h = hist[i];
        base[i] = h ? atomicAdd(&cursor[i], h) : 0;
        hist[i] = 0;                         // reuse as local cursor
    }
    __syncthreads();
    for (int i = tid; i < SLICE; i += 256) {
        int b = s_bk[i];
        int off = base[b] + atomicAdd(&hist[b], 1);
        if (off < BCAP) ebuf[b * BCAP + off] = s_pk[i];
    }
}

// per-bucket local counting sort -> deg/inv_deg/row_ptr + coalesced csr write.
// bucket base offset computed inline (sum of cursor[0..b)) - no bscan kernel.
__global__ __launch_bounds__(256) void fillb_kernel(
        const int* __restrict__ cursor, const int* __restrict__ ebuf,
        int* __restrict__ row_ptr, float* __restrict__ inv_deg,
        int* __restrict__ csr_src) {
    __shared__ int lcsr[BCAP];
    __shared__ int hist[128], lofs[128];
    __shared__ int wtot[2];
    __shared__ int sred[4];
    __shared__ int sbase;
    const int b = blockIdx.x;
    const int tid = threadIdx.x;

    int partial = 0;
    for (int i = tid; i < b; i += 256) partial += cursor[i];
    #pragma unroll
    for (int off = 1; off < 64; off <<= 1) partial += __shfl_xor(partial, off, 64);
    if ((tid & 63) == 0) sred[tid >> 6] = partial;
    if (tid < 128) hist[tid] = 0;
    __syncthreads();
    if (tid == 0) sbase = sred[0] + sred[1] + sred[2] + sred[3];
    __syncthreads();
    const int base = sbase;

    int cnt = cursor[b]; if (cnt > BCAP) cnt = BCAP;
    const int* eb = ebuf + b * BCAP;

    for (int i = tid; i < cnt; i += 256) atomicAdd(&hist[eb[i] >> 16], 1);
    __syncthreads();
    if (tid < 128) {
        int lane = tid & 63;
        int v = hist[tid];
        int inc = v;
        #pragma unroll
        for (int off = 1; off < 64; off <<= 1) {
            int t = __shfl_up(inc, off, 64);
            if (lane >= off) inc += t;
        }
        lofs[tid] = inc - v;
        if (lane == 63) wtot[tid >> 6] = inc;
    }
    __syncthreads();
    if (tid >= 64 && tid < 128) lofs[tid] += wtot[0];
    __syncthreads();
    if (tid < 128) {
        int node = b * 128 + tid;
        if (node < N_NODES) {
            row_ptr[node] = base + lofs[tid];
            int d = hist[tid];
            inv_deg[node] = (d > 0) ? (1.0f / (float)d) : 0.0f;
        }
        hist[tid] = lofs[tid];               // running local cursor
    }
    if (b == 0 && tid == 0) row_ptr[N_NODES] = N_EDGES;
    __syncthreads();
    for (int i = tid; i < cnt; i += 256) {
        int pk = eb[i];
        int p = atomicAdd(&hist[pk >> 16], 1);
        lcsr[p] = pk & 0xFFFF;
    }
    __syncthreads();
    for (int i = tid; i < cnt; i += 256) csr_src[base + i] = lcsr[i];
}

// ---------------------------------------------------------------------------
// mean aggregation (R6-proven): wave per node, split 32/32 so one 8B/lane
// dwordx2 gather covers TWO edges (512 B); x4 unroll for MLP.
__global__ void agg_kernel(const __hip_bfloat16* __restrict__ x, const int* __restrict__ row_ptr,
                           const int* __restrict__ csr_src, const float* __restrict__ inv_deg,
                           __hip_bfloat16* __restrict__ agg) {
    int gid = blockIdx.x * blockDim.x + threadIdx.x;
    int node = gid >> 6;
    int lane = threadIdx.x & 63;
    if (node >= N_NODES) return;
    const int half = lane >> 5;
    const int l32  = lane & 31;
    const int beg = row_ptr[node], end = row_ptr[node + 1];

    float a[4][4];
    #pragma unroll
    for (int u = 0; u < 4; ++u)
        #pragma unroll
        for (int k = 0; k < 4; ++k) a[u][k] = 0.f;

    for (int c = beg; c < end; c += 64) {
        int ei = c + lane;
        int sidx = (ei < end) ? csr_src[ei] : 0;
        int nedge = end - c; if (nedge > 64) nedge = 64;
        int npair = nedge >> 1;
        int j = 0;
        for (; j + 4 <= npair; j += 4) {
            #pragma unroll
            for (int u = 0; u < 4; ++u) {
                int sj = __shfl(sidx, 2 * (j + u) + half, 64);
                float2 v = ((const float2*)(x + (size_t)sj * HIDDEN))[l32];
                __hip_bfloat162 b0 = *(__hip_bfloat162*)&v.x;
                __hip_bfloat162 b1 = *(__hip_bfloat162*)&v.y;
                a[u][0] += __bfloat162float(b0.x);
                a[u][1] += __bfloat162float(b0.y);
                a[u][2] += __bfloat162float(b1.x);
                a[u][3] += __bfloat162float(b1.y);
            }
        }
        for (; j < npair; ++j) {
            int sj = __shfl(sidx, 2 * j + half, 64);
            float2 v = ((const float2*)(x + (size_t)sj * HIDDEN))[l32];
            __hip_bfloat162 b0 = *(__hip_bfloat162*)&v.x;
            __hip_bfloat162 b1 = *(__hip_bfloat162*)&v.y;
            a[0][0] += __bfloat162float(b0.x);
            a[0][1] += __bfloat162float(b0.y);
            a[0][2] += __bfloat162float(b1.x);
            a[0][3] += __bfloat162float(b1.y);
        }
        if (nedge & 1) {
            int sj = __shfl(sidx, nedge - 1, 64);
            if (half == 0) {
                float2 v = ((const float2*)(x + (size_t)sj * HIDDEN))[l32];
                __hip_bfloat162 b0 = *(__hip_bfloat162*)&v.x;
                __hip_bfloat162 b1 = *(__hip_bfloat162*)&v.y;
                a[0][0] += __bfloat162float(b0.x);
                a[0][1] += __bfloat162float(b0.y);
                a[0][2] += __bfloat162float(b1.x);
                a[0][3] += __bfloat162float(b1.y);
            }
        }
    }

    float s0 = a[0][0] + a[1][0] + a[2][0] + a[3][0];
    float s1 = a[0][1] + a[1][1] + a[2][1] + a[3][1];
    float s2 = a[0][2] + a[1][2] + a[2][2] + a[3][2];
    float s3 = a[0][3] + a[1][3] + a[2][3] + a[3][3];
    s0 += __shfl_xor(s0, 32, 64);
    s1 += __shfl_xor(s1, 32, 64);
    s2 += __shfl_xor(s2, 32, 64);
    s3 += __shfl_xor(s3, 32, 64);

    if (half == 0) {
        float w = inv_deg[node];
        __hip_bfloat162 p0, p1;
        p0.x = __float2bfloat16(s0 * w);
        p0.y = __float2bfloat16(s1 * w);
        p1.x = __float2bfloat16(s2 * w);
        p1.y = __float2bfloat16(s3 * w);
        __hip_bfloat162* op = (__hip_bfloat162*)agg + (size_t)node * 64 + l32 * 2;
        op[0] = p0;
        op[1] = p1;
    }
}

// ---------------------------------------------------------------------------
// Shared GEMM body macro-free: two variants share everything up to the epilogue.
#define GM 64

// layer-1 variant: writes bf16 xout
__global__ __launch_bounds__(256) void gemm_mfma_ln_kernel(
        const __hip_bfloat16* __restrict__ aggb, const __hip_bfloat16* __restrict__ xb,
        __hip_bfloat16* __restrict__ xout,
        const __hip_bfloat16* __restrict__ Wt,
        const float* __restrict__ brel, const float* __restrict__ gamma,
        const float* __restrict__ beta) {
    __shared__ __align__(16) short sA[GM * 264];
    __shared__ float red[GM][4][2];

    const int tid  = threadIdx.x;
    const int w    = tid >> 6;
    const int lane = tid & 63;
    const int q    = lane >> 4;
    const int l15  = lane & 15;
    const int base = blockIdx.x * GM;

    short8 breg[2][8];
    #pragma unroll
    for (int nt = 0; nt < 2; ++nt) {
        int col = 32 * w + nt * 16 + l15;
        const short* wp = (const short*)Wt + (size_t)col * 256;
        #pragma unroll
        for (int ks = 0; ks < 8; ++ks)
            breg[nt][ks] = *(const short8*)(wp + ks * 32 + q * 8);
    }

    for (int it = 0; it < 8; ++it) {
        int c = it * 256 + tid;
        int row = c >> 5, cc = c & 31;
        int node = base + row;
        short8 v = {0,0,0,0,0,0,0,0};
        if (node < N_NODES) {
            const short* gp = (cc < 16)
                ? (const short*)aggb + (size_t)node * HIDDEN + cc * 8
                : (const short*)xb   + (size_t)node * HIDDEN + (cc - 16) * 8;
            v = *(const short8*)gp;
        }
        *(short8*)&sA[row * 264 + cc * 8] = v;
    }
    __syncthreads();

    f32x4 acc[4][2];
    #pragma unroll
    for (int mt = 0; mt < 4; ++mt)
        #pragma unroll
        for (int nt = 0; nt < 2; ++nt)
            acc[mt][nt] = (f32x4){0.f, 0.f, 0.f, 0.f};

    #pragma unroll
    for (int ks = 0; ks < 8; ++ks) {
        short8 a[4];
        #pragma unroll
        for (int mt = 0; mt < 4; ++mt)
            a[mt] = *(short8*)&sA[(mt * 16 + l15) * 264 + ks * 32 + q * 8];
        #pragma unroll
        for (int mt = 0; mt < 4; ++mt) {
            acc[mt][0] = __builtin_amdgcn_mfma_f32_16x16x32_bf16(a[mt], breg[0][ks], acc[mt][0], 0, 0, 0);
            acc[mt][1] = __builtin_amdgcn_mfma_f32_16x16x32_bf16(a[mt], breg[1][ks], acc[mt][1], 0, 0, 0);
        }
    }

    const int col0 = 32 * w + l15, col1 = col0 + 16;
    const float b0 = brel[col0], b1 = brel[col1];
    #pragma unroll
    for (int mt = 0; mt < 4; ++mt) {
        #pragma unroll
        for (int r = 0; r < 4; ++r) {
            acc[mt][0][r] += b0;
            acc[mt][1][r] += b1;
            float s  = acc[mt][0][r] + acc[mt][1][r];
            float s2 = acc[mt][0][r] * acc[mt][0][r] + acc[mt][1][r] * acc[mt][1][r];
            #pragma unroll
            for (int off = 1; off < 16; off <<= 1) {
                s  += __shfl_xor(s,  off, 64);
                s2 += __shfl_xor(s2, off, 64);
            }
            if (l15 == 0) {
                red[mt * 16 + q * 4 + r][w][0] = s;
                red[mt * 16 + q * 4 + r][w][1] = s2;
            }
        }
    }
    __syncthreads();

    const float g0 = gamma[col0], g1 = gamma[col1];
    const float e0 = beta[col0],  e1 = beta[col1];
    #pragma unroll
    for (int mt = 0; mt < 4; ++mt) {
        #pragma unroll
        for (int r = 0; r < 4; ++r) {
            int row = mt * 16 + q * 4 + r;
            float tot  = red[row][0][0] + red[row][1][0] + red[row][2][0] + red[row][3][0];
            float tot2 = red[row][0][1] + red[row][1][1] + red[row][2][1] + red[row][3][1];
            float mu  = tot * (1.0f / HIDDEN);
            float var = tot2 * (1.0f / HIDDEN) - mu * mu;
            float rs  = rsqrtf(var + EPS);
            int node = base + row;
            if (node < N_NODES) {
                float v0 = fmaxf(g0 * (acc[mt][0][r] - mu) * rs + e0, 0.f);
                float v1 = fmaxf(g1 * (acc[mt][1][r] - mu) * rs + e1, 0.f);
                xout[(size_t)node * HIDDEN + col0] = __float2bfloat16(v0);
                xout[(size_t)node * HIDDEN + col1] = __float2bfloat16(v1);
            }
        }
    }
}

// layer-2 variant: instead of writing x2, mean-pool contributions go straight
// to pooled[] via per-block pre-reduction + few atomics (batch is sorted ->
// a 64-node block spans 1-2 graphs).
__global__ __launch_bounds__(256) void gemm_mfma_pool_kernel(
        const __hip_bfloat16* __restrict__ aggb, const __hip_bfloat16* __restrict__ xb,
        const int* __restrict__ batch, float* __restrict__ pooled,
        const __hip_bfloat16* __restrict__ Wt,
        const float* __restrict__ brel, const float* __restrict__ gamma,
        const float* __restrict__ beta) {
    __shared__ __align__(16) short sA[GM * 264];
    __shared__ float red[GM][4][2];
    __shared__ int sbatch[GM];

    const int tid  = threadIdx.x;
    const int w    = tid >> 6;
    const int lane = tid & 63;
    const int q    = lane >> 4;
    const int l15  = lane & 15;
    const int base = blockIdx.x * GM;

    if (tid < GM) {
        int node = base + tid;
        sbatch[tid] = (node < N_NODES) ? batch[node] : -1;
    }

    short8 breg[2][8];
    #pragma unroll
    for (int nt = 0; nt < 2; ++nt) {
        int col = 32 * w + nt * 16 + l15;
        const short* wp = (const short*)Wt + (size_t)col * 256;
        #pragma unroll
        for (int ks = 0; ks < 8; ++ks)
            breg[nt][ks] = *(const short8*)(wp + ks * 32 + q * 8);
    }

    for (int it = 0; it < 8; ++it) {
        int c = it * 256 + tid;
        int row = c >> 5, cc = c & 31;
        int node = base + row;
        short8 v = {0,0,0,0,0,0,0,0};
        if (node < N_NODES) {
            const short* gp = (cc < 16)
                ? (const short*)aggb + (size_t)node * HIDDEN + cc * 8
                : (const short*)xb   + (size_t)node * HIDDEN + (cc - 16) * 8;
            v = *(const short8*)gp;
        }
        *(short8*)&sA[row * 264 + cc * 8] = v;
    }
    __syncthreads();

    f32x4 acc[4][2];
    #pragma unroll
    for (int mt = 0; mt < 4; ++mt)
        #pragma unroll
        for (int nt = 0; nt < 2; ++nt)
            acc[mt][nt] = (f32x4){0.f, 0.f, 0.f, 0.f};

    #pragma unroll
    for (int ks = 0; ks < 8; ++ks) {
        short8 a[4];
        #pragma unroll
        for (int mt = 0; mt < 4; ++mt)
            a[mt] = *(short8*)&sA[(mt * 16 + l15) * 264 + ks * 32 + q * 8];
        #pragma unroll
        for (int mt = 0; mt < 4; ++mt) {
            acc[mt][0] = __builtin_amdgcn_mfma_f32_16x16x32_bf16(a[mt], breg[0][ks], acc[mt][0], 0, 0, 0);
            acc[mt][1] = __builtin_amdgcn_mfma_f32_16x16x32_bf16(a[mt], breg[1][ks], acc[mt][1], 0, 0, 0);
        }
    }

    const int col0 = 32 * w + l15, col1 = col0 + 16;
    const float b0 = brel[col0], b1 = brel[col1];
    #pragma unroll
    for (int mt = 0; mt < 4; ++mt) {
        #pragma unroll
        for (int r = 0; r < 4; ++r) {
            acc[mt][0][r] += b0;
            acc[mt][1][r] += b1;
            float s  = acc[mt][0][r] + acc[mt][1][r];
            float s2 = acc[mt][0][r] * acc[mt][0][r] + acc[mt][1][r] * acc[mt][1][r];
            #pragma unroll
            for (int off = 1; off < 16; off <<= 1) {
                s  += __shfl_xor(s,  off, 64);
                s2 += __shfl_xor(s2, off, 64);
            }
            if (l15 == 0) {
                red[mt * 16 + q * 4 + r][w][0] = s;
                red[mt * 16 + q * 4 + r][w][1] = s2;
            }
        }
    }
    __syncthreads();

    const float g0 = gamma[col0], g1 = gamma[col1];
    const float e0 = beta[col0],  e1 = beta[col1];
    // overwrite acc with post-LN/ReLU values (0 for out-of-range rows)
    #pragma unroll
    for (int mt = 0; mt < 4; ++mt) {
        #pragma unroll
        for (int r = 0; r < 4; ++r) {
            int row = mt * 16 + q * 4 + r;
            float tot  = red[row][0][0] + red[row][1][0] + red[row][2][0] + red[row][3][0];
            float tot2 = red[row][0][1] + red[row][1][1] + red[row][2][1] + red[row][3][1];
            float mu  = tot * (1.0f / HIDDEN);
            float var = tot2 * (1.0f / HIDDEN) - mu * mu;
            float rs  = rsqrtf(var + EPS);
            bool valid = (base + row) < N_NODES;
            float v0 = valid ? fmaxf(g0 * (acc[mt][0][r] - mu) * rs + e0, 0.f) : 0.f;
            float v1 = valid ? fmaxf(g1 * (acc[mt][1][r] - mu) * rs + e1, 0.f) : 0.f;
            acc[mt][0][r] = v0;
            acc[mt][1][r] = v1;
        }
    }

    // per-graph pre-reduction over this block's rows, then 1 atomic/col/graph
    int idxmax = N_NODES - 1 - base; if (idxmax > GM - 1) idxmax = GM - 1;
    const int gmin = sbatch[0], gmax = sbatch[idxmax];
    for (int g = gmin; g <= gmax; ++g) {
        float p0 = 0.f, p1 = 0.f;
        #pragma unroll
        for (int mt = 0; mt < 4; ++mt) {
            #pragma unroll
            for (int r = 0; r < 4; ++r) {
                int row = mt * 16 + q * 4 + r;
                if (sbatch[row] == g) { p0 += acc[mt][0][r]; p1 += acc[mt][1][r]; }
            }
        }
        p0 += __shfl_xor(p0, 16, 64); p0 += __shfl_xor(p0, 32, 64);
        p1 += __shfl_xor(p1, 16, 64); p1 += __shfl_xor(p1, 32, 64);
        if (q == 0) {
            atomicAdd(&pooled[g * HIDDEN + col0], p0);
            atomicAdd(&pooled[g * HIDDEN + col1], p1);
        }
    }
}

// head (derives per-graph counts from the sorted batch array)
__global__ void out_kernel(const float* __restrict__ pooled, const int* __restrict__ batch,
                           const float* __restrict__ Wc, const float* __restrict__ bc,
                           float* __restrict__ out) {
    int idx = blockIdx.x * blockDim.x + threadIdx.x;
    if (idx >= N_GRAPHS * OUT_F) return;
    int g = idx / OUT_F, o = idx % OUT_F;
    int lo = 0, hi = N_NODES;
    while (lo < hi) { int m = (lo + hi) >> 1; if (batch[m] < g) lo = m + 1; else hi = m; }
    int b0 = lo;
    lo = 0; hi = N_NODES;
    while (lo < hi) { int m = (lo + hi) >> 1; if (batch[m] < g + 1) lo = m + 1; else hi = m; }
    float cntf = (float)(lo - b0);
    float inv = 1.0f / fmaxf(cntf, 1.0f);
    float s = 0.f;
    for (int f = 0; f < HIDDEN; ++f)
        s += pooled[g * HIDDEN + f] * Wc[f * OUT_F + o];
    out[idx] = s * inv + bc[o];
}

// ---------------------------------------------------------------------------
static inline size_t align256(size_t v) { return (v + 255) & ~(size_t)255; }

extern "C" void kernel_launch(void* const* d_in, const int* in_sizes, int n_in,
                              void* d_out, int out_size, void* d_ws, size_t ws_size,
                              hipStream_t stream) {
    const float* x      = (const float*)d_in[0];
    const int*   eidx   = (const int*)d_in[1];
    const int*   batch  = (const int*)d_in[2];
    const float* W_rel  = (const float*)d_in[3];
    const float* b_rel  = (const float*)d_in[4];
    const float* W_root = (const float*)d_in[5];
    const float* gamma  = (const float*)d_in[6];
    const float* beta   = (const float*)d_in[7];
    const float* Wc     = (const float*)d_in[8];
    const float* bc     = (const float*)d_in[9];
    float* out = (float*)d_out;

    const int* src = eidx;
    const int* dst = eidx + N_EDGES;

    char* ws = (char*)d_ws;
    size_t off = 0;
    int*   row_ptr  = (int*)(ws + off);  off = align256(off + sizeof(int) * (N_NODES + 1));
    int*   csr_src  = (int*)(ws + off);  off = align256(off + sizeof(int) * N_EDGES);
    float* inv_deg  = (float*)(ws + off); off = align256(off + sizeof(float) * N_NODES);
    int*   cursor   = (int*)(ws + off);  off = align256(off + sizeof(int) * NB);
    int*   ebuf     = (int*)(ws + off);  off = align256(off + sizeof(int) * (size_t)NB * BCAP);
    __hip_bfloat16* x0b  = (__hip_bfloat16*)(ws + off); off = align256(off + 2 * (size_t)N_NODES * HIDDEN);
    __hip_bfloat16* x1b  = (__hip_bfloat16*)(ws + off); off = align256(off + 2 * (size_t)N_NODES * HIDDEN);
    __hip_bfloat16* aggb = (__hip_bfloat16*)(ws + off); off = align256(off + 2 * (size_t)N_NODES * HIDDEN);
    __hip_bfloat16* Wt   = (__hip_bfloat16*)(ws + off); off = align256(off + 2 * (size_t)2 * HIDDEN * 256);
    float* pooled   = (float*)(ws + off); off = align256(off + sizeof(float) * N_GRAPHS * HIDDEN);

    // casts + zero-init (cursor, pooled) in one launch
    cast_zero_kernel<<<CASTX_BLOCKS + CASTW_BLOCKS + POOLZ_BLOCKS + 1, 256, 0, stream>>>(
        x, x0b, W_rel, W_root, Wt, cursor, pooled);

    // CSR build via bucket partition (once; reused by both layers)
    part_kernel <<<256, 256, 0, stream>>>(src, dst, cursor, ebuf);
    fillb_kernel<<<NB, 256, 0, stream>>>(cursor, ebuf, row_ptr, inv_deg, csr_src);

    const int agg_blocks  = (N_NODES * 64) / 256;      // 12500
    const int gemm_blocks = (N_NODES + GM - 1) / GM;   // 782

    // layer 0
    agg_kernel<<<agg_blocks, 256, 0, stream>>>(x0b, row_ptr, csr_src, inv_deg, aggb);
    gemm_mfma_ln_kernel<<<gemm_blocks, 256, 0, stream>>>(
        aggb, x0b, x1b, Wt, b_rel, gamma, beta);
    // layer 1: gemm fuses mean-pool epilogue (no x2 buffer at all)
    agg_kernel<<<agg_blocks, 256, 0, stream>>>(x1b, row_ptr, csr_src, inv_deg, aggb);
    gemm_mfma_pool_kernel<<<gemm_blocks, 256, 0, stream>>>(
        aggb, x1b, batch, pooled, Wt + 2 * HIDDEN * 256 / 2,
        b_rel + HIDDEN, gamma + HIDDEN, beta + HIDDEN);

    // head
    out_kernel<<<(N_GRAPHS * OUT_F + 255) / 256, 256, 0, stream>>>(pooled, batch, Wc, bc, out);
}

// Round 10
// 216.533 us; speedup vs baseline: 1.6014x; 1.0618x over previous
//
#include <hip/hip_runtime.h>
#include <hip/hip_bf16.h>
#include <hip/hip_fp8.h>

#define N_NODES 50000
#define N_EDGES 800000
#define HIDDEN  128
#define OUT_F   10
#define N_GRAPHS 128
#define EPS 1e-5f

#define NB   391                    // ceil(50000/128) buckets of 128 nodes
#define BCAP 3072                   // bucket capacity (mean 2048)
#define SLICE (N_EDGES / 256)       // 3125 edges per partition block

// merged prep kernel block ranges (part first: it's the critical path)
#define PART_B0   0
#define CASTW_B0  256
#define POOLZ_B0  512
#define CASTX_B0  576
#define CASTX_NB  6250              // N_NODES*HIDDEN/4 quads / 256
#define PREP_NB   (CASTX_B0 + CASTX_NB)

using short8 = __attribute__((ext_vector_type(8))) short;
using f32x4  = __attribute__((ext_vector_type(4))) float;

// ---------------------------------------------------------------------------
// fp8 helpers (OCP e4m3), HW cvt when available
__device__ __forceinline__ unsigned int f4_to_fp8x4(float a, float b, float c, float d) {
#if __has_builtin(__builtin_amdgcn_cvt_pk_fp8_f32)
    int v = 0;
    v = __builtin_amdgcn_cvt_pk_fp8_f32(a, b, v, false);
    v = __builtin_amdgcn_cvt_pk_fp8_f32(c, d, v, true);
    return (unsigned int)v;
#else
    __hip_fp8_e4m3 ha(a), hb(b), hc(c), hd(d);
    return (unsigned int)ha.__x | ((unsigned int)hb.__x << 8) |
           ((unsigned int)hc.__x << 16) | ((unsigned int)hd.__x << 24);
#endif
}
__device__ __forceinline__ unsigned char f_to_fp8(float a) {
#if __has_builtin(__builtin_amdgcn_cvt_pk_fp8_f32)
    return (unsigned char)(__builtin_amdgcn_cvt_pk_fp8_f32(a, a, 0, false) & 0xff);
#else
    __hip_fp8_e4m3 h(a); return h.__x;
#endif
}
__device__ __forceinline__ void fp8x4_to_f(unsigned int w, float o[4]) {
#if __has_builtin(__builtin_amdgcn_cvt_pk_f32_fp8)
    typedef float v2f __attribute__((ext_vector_type(2)));
    v2f lo = __builtin_amdgcn_cvt_pk_f32_fp8((int)w, false);
    v2f hi = __builtin_amdgcn_cvt_pk_f32_fp8((int)w, true);
    o[0] = lo.x; o[1] = lo.y; o[2] = hi.x; o[3] = hi.y;
#else
    #pragma unroll
    for (int t = 0; t < 4; ++t) {
        __hip_fp8_e4m3 h; h.__x = (unsigned char)((w >> (8 * t)) & 0xff);
        o[t] = (float)h;
    }
#endif
}

// ---------------------------------------------------------------------------
// merged prep: edge bucket-partition (part) + W cast + pooled zero + x cast
// (x -> bf16 x0b AND fp8 x0f). cursor must be zeroed (memset) beforehand.
__global__ __launch_bounds__(256) void prep_kernel(
        const float* __restrict__ x, __hip_bfloat16* __restrict__ x0b,
        unsigned char* __restrict__ x0f,
        const float* __restrict__ Wrel, const float* __restrict__ Wroot,
        __hip_bfloat16* __restrict__ Wt,
        const int* __restrict__ src, const int* __restrict__ dst,
        int* __restrict__ cursor, int* __restrict__ ebuf,
        float* __restrict__ pooled) {
    __shared__ int s_pk[SLICE];
    __shared__ unsigned short s_bk[SLICE];
    __shared__ int hist[NB], base[NB];
    const int b = blockIdx.x, tid = threadIdx.x;

    if (b < CASTW_B0) {
        // ---- edge partition by dst>>7, packed src | (dst&127)<<16 ----
        const int e0 = b * SLICE;
        for (int i = tid; i < NB; i += 256) hist[i] = 0;
        __syncthreads();
        for (int i = tid; i < SLICE; i += 256) {
            int s = src[e0 + i], d = dst[e0 + i];
            int bk = d >> 7;
            s_pk[i] = s | ((d & 127) << 16);
            s_bk[i] = (unsigned short)bk;
            atomicAdd(&hist[bk], 1);
        }
        __syncthreads();
        for (int i = tid; i < NB; i += 256) {
            int h = hist[i];
            base[i] = h ? atomicAdd(&cursor[i], h) : 0;
            hist[i] = 0;
        }
        __syncthreads();
        for (int i = tid; i < SLICE; i += 256) {
            int bk = s_bk[i];
            int off = base[bk] + atomicAdd(&hist[bk], 1);
            if (off < BCAP) ebuf[bk * BCAP + off] = s_pk[i];
        }
    } else if (b < POOLZ_B0) {
        // ---- W cast: Wt[l][n][k] transposed concat [W_rel;W_root] ----
        int idx = (b - CASTW_B0) * 256 + tid;        // 65536
        int l = idx >> 15;
        int rem = idx & 32767;
        int n = rem >> 8;
        int k = rem & 255;
        float v = (k < HIDDEN) ? Wrel[l * HIDDEN * HIDDEN + k * HIDDEN + n]
                               : Wroot[l * HIDDEN * HIDDEN + (k - HIDDEN) * HIDDEN + n];
        Wt[idx] = __float2bfloat16(v);
    } else if (b < CASTX_B0) {
        int i = (b - POOLZ_B0) * 256 + tid;          // 16384
        pooled[i] = 0.f;
    } else {
        // ---- x cast: one float4 per thread -> 4 bf16 + 4 fp8 ----
        int i = (b - CASTX_B0) * 256 + tid;          // quad index, 1.6M
        float4 v = ((const float4*)x)[i];
        union { __hip_bfloat162 h[2]; uint2 u; } o;
        o.h[0].x = __float2bfloat16(v.x);
        o.h[0].y = __float2bfloat16(v.y);
        o.h[1].x = __float2bfloat16(v.z);
        o.h[1].y = __float2bfloat16(v.w);
        ((uint2*)x0b)[i] = o.u;
        ((unsigned int*)x0f)[i] = f4_to_fp8x4(v.x, v.y, v.z, v.w);
    }
}

// per-bucket local counting sort -> deg/inv_deg/row_ptr + coalesced csr write.
__global__ __launch_bounds__(256) void fillb_kernel(
        const int* __restrict__ cursor, const int* __restrict__ ebuf,
        int* __restrict__ row_ptr, float* __restrict__ inv_deg,
        int* __restrict__ csr_src) {
    __shared__ int lcsr[BCAP];
    __shared__ int hist[128], lofs[128];
    __shared__ int wtot[2];
    __shared__ int sred[4];
    __shared__ int sbase;
    const int b = blockIdx.x;
    const int tid = threadIdx.x;

    int partial = 0;
    for (int i = tid; i < b; i += 256) partial += cursor[i];
    #pragma unroll
    for (int off = 1; off < 64; off <<= 1) partial += __shfl_xor(partial, off, 64);
    if ((tid & 63) == 0) sred[tid >> 6] = partial;
    if (tid < 128) hist[tid] = 0;
    __syncthreads();
    if (tid == 0) sbase = sred[0] + sred[1] + sred[2] + sred[3];
    __syncthreads();
    const int base = sbase;

    int cnt = cursor[b]; if (cnt > BCAP) cnt = BCAP;
    const int* eb = ebuf + b * BCAP;

    for (int i = tid; i < cnt; i += 256) atomicAdd(&hist[eb[i] >> 16], 1);
    __syncthreads();
    if (tid < 128) {
        int lane = tid & 63;
        int v = hist[tid];
        int inc = v;
        #pragma unroll
        for (int off = 1; off < 64; off <<= 1) {
            int t = __shfl_up(inc, off, 64);
            if (lane >= off) inc += t;
        }
        lofs[tid] = inc - v;
        if (lane == 63) wtot[tid >> 6] = inc;
    }
    __syncthreads();
    if (tid >= 64 && tid < 128) lofs[tid] += wtot[0];
    __syncthreads();
    if (tid < 128) {
        int node = b * 128 + tid;
        if (node < N_NODES) {
            row_ptr[node] = base + lofs[tid];
            int d = hist[tid];
            inv_deg[node] = (d > 0) ? (1.0f / (float)d) : 0.0f;
        }
        hist[tid] = lofs[tid];
    }
    if (b == 0 && tid == 0) row_ptr[N_NODES] = N_EDGES;
    __syncthreads();
    for (int i = tid; i < cnt; i += 256) {
        int pk = eb[i];
        int p = atomicAdd(&hist[pk >> 16], 1);
        lcsr[p] = pk & 0xFFFF;
    }
    __syncthreads();
    for (int i = tid; i < cnt; i += 256) csr_src[base + i] = lcsr[i];
}

// ---------------------------------------------------------------------------
// mean aggregation, fp8 gather (128 B rows): wave per node, split 32/32 so one
// 4B/lane dword gather covers TWO edges (256 B); x4 unroll; fp32 accumulate;
// bf16 output. Feature mapping per lane: 4*l32..4*l32+3 (same as R6).
__global__ void agg_kernel(const unsigned char* __restrict__ xf8, const int* __restrict__ row_ptr,
                           const int* __restrict__ csr_src, const float* __restrict__ inv_deg,
                           __hip_bfloat16* __restrict__ agg) {
    int gid = blockIdx.x * blockDim.x + threadIdx.x;
    int node = gid >> 6;
    int lane = threadIdx.x & 63;
    if (node >= N_NODES) return;
    const int half = lane >> 5;
    const int l32  = lane & 31;
    const int beg = row_ptr[node], end = row_ptr[node + 1];

    float a[4][4];
    #pragma unroll
    for (int u = 0; u < 4; ++u)
        #pragma unroll
        for (int k = 0; k < 4; ++k) a[u][k] = 0.f;

    for (int c = beg; c < end; c += 64) {
        int ei = c + lane;
        int sidx = (ei < end) ? csr_src[ei] : 0;
        int nedge = end - c; if (nedge > 64) nedge = 64;
        int npair = nedge >> 1;
        int j = 0;
        for (; j + 4 <= npair; j += 4) {
            #pragma unroll
            for (int u = 0; u < 4; ++u) {
                int sj = __shfl(sidx, 2 * (j + u) + half, 64);
                unsigned int wv = ((const unsigned int*)(xf8 + (size_t)sj * HIDDEN))[l32];
                float f[4];
                fp8x4_to_f(wv, f);
                a[u][0] += f[0]; a[u][1] += f[1]; a[u][2] += f[2]; a[u][3] += f[3];
            }
        }
        for (; j < npair; ++j) {
            int sj = __shfl(sidx, 2 * j + half, 64);
            unsigned int wv = ((const unsigned int*)(xf8 + (size_t)sj * HIDDEN))[l32];
            float f[4];
            fp8x4_to_f(wv, f);
            a[0][0] += f[0]; a[0][1] += f[1]; a[0][2] += f[2]; a[0][3] += f[3];
        }
        if (nedge & 1) {
            int sj = __shfl(sidx, nedge - 1, 64);
            if (half == 0) {
                unsigned int wv = ((const unsigned int*)(xf8 + (size_t)sj * HIDDEN))[l32];
                float f[4];
                fp8x4_to_f(wv, f);
                a[0][0] += f[0]; a[0][1] += f[1]; a[0][2] += f[2]; a[0][3] += f[3];
            }
        }
    }

    float s0 = a[0][0] + a[1][0] + a[2][0] + a[3][0];
    float s1 = a[0][1] + a[1][1] + a[2][1] + a[3][1];
    float s2 = a[0][2] + a[1][2] + a[2][2] + a[3][2];
    float s3 = a[0][3] + a[1][3] + a[2][3] + a[3][3];
    s0 += __shfl_xor(s0, 32, 64);
    s1 += __shfl_xor(s1, 32, 64);
    s2 += __shfl_xor(s2, 32, 64);
    s3 += __shfl_xor(s3, 32, 64);

    if (half == 0) {
        float w = inv_deg[node];
        __hip_bfloat162 p0, p1;
        p0.x = __float2bfloat16(s0 * w);
        p0.y = __float2bfloat16(s1 * w);
        p1.x = __float2bfloat16(s2 * w);
        p1.y = __float2bfloat16(s3 * w);
        __hip_bfloat162* op = (__hip_bfloat162*)agg + (size_t)node * 64 + l32 * 2;
        op[0] = p0;
        op[1] = p1;
    }
}

// ---------------------------------------------------------------------------
#define GM 64

// layer-1 GEMM: writes bf16 xout AND fp8 xoutf (for the layer-2 gather)
__global__ __launch_bounds__(256) void gemm_mfma_ln_kernel(
        const __hip_bfloat16* __restrict__ aggb, const __hip_bfloat16* __restrict__ xb,
        __hip_bfloat16* __restrict__ xout, unsigned char* __restrict__ xoutf,
        const __hip_bfloat16* __restrict__ Wt,
        const float* __restrict__ brel, const float* __restrict__ gamma,
        const float* __restrict__ beta) {
    __shared__ __align__(16) short sA[GM * 264];
    __shared__ float red[GM][4][2];

    const int tid  = threadIdx.x;
    const int w    = tid >> 6;
    const int lane = tid & 63;
    const int q    = lane >> 4;
    const int l15  = lane & 15;
    const int base = blockIdx.x * GM;

    short8 breg[2][8];
    #pragma unroll
    for (int nt = 0; nt < 2; ++nt) {
        int col = 32 * w + nt * 16 + l15;
        const short* wp = (const short*)Wt + (size_t)col * 256;
        #pragma unroll
        for (int ks = 0; ks < 8; ++ks)
            breg[nt][ks] = *(const short8*)(wp + ks * 32 + q * 8);
    }

    for (int it = 0; it < 8; ++it) {
        int c = it * 256 + tid;
        int row = c >> 5, cc = c & 31;
        int node = base + row;
        short8 v = {0,0,0,0,0,0,0,0};
        if (node < N_NODES) {
            const short* gp = (cc < 16)
                ? (const short*)aggb + (size_t)node * HIDDEN + cc * 8
                : (const short*)xb   + (size_t)node * HIDDEN + (cc - 16) * 8;
            v = *(const short8*)gp;
        }
        *(short8*)&sA[row * 264 + cc * 8] = v;
    }
    __syncthreads();

    f32x4 acc[4][2];
    #pragma unroll
    for (int mt = 0; mt < 4; ++mt)
        #pragma unroll
        for (int nt = 0; nt < 2; ++nt)
            acc[mt][nt] = (f32x4){0.f, 0.f, 0.f, 0.f};

    #pragma unroll
    for (int ks = 0; ks < 8; ++ks) {
        short8 a[4];
        #pragma unroll
        for (int mt = 0; mt < 4; ++mt)
            a[mt] = *(short8*)&sA[(mt * 16 + l15) * 264 + ks * 32 + q * 8];
        #pragma unroll
        for (int mt = 0; mt < 4; ++mt) {
            acc[mt][0] = __builtin_amdgcn_mfma_f32_16x16x32_bf16(a[mt], breg[0][ks], acc[mt][0], 0, 0, 0);
            acc[mt][1] = __builtin_amdgcn_mfma_f32_16x16x32_bf16(a[mt], breg[1][ks], acc[mt][1], 0, 0, 0);
        }
    }

    const int col0 = 32 * w + l15, col1 = col0 + 16;
    const float b0 = brel[col0], b1 = brel[col1];
    #pragma unroll
    for (int mt = 0; mt < 4; ++mt) {
        #pragma unroll
        for (int r = 0; r < 4; ++r) {
            acc[mt][0][r] += b0;
            acc[mt][1][r] += b1;
            float s  = acc[mt][0][r] + acc[mt][1][r];
            float s2 = acc[mt][0][r] * acc[mt][0][r] + acc[mt][1][r] * acc[mt][1][r];
            #pragma unroll
            for (int off = 1; off < 16; off <<= 1) {
                s  += __shfl_xor(s,  off, 64);
                s2 += __shfl_xor(s2, off, 64);
            }
            if (l15 == 0) {
                red[mt * 16 + q * 4 + r][w][0] = s;
                red[mt * 16 + q * 4 + r][w][1] = s2;
            }
        }
    }
    __syncthreads();

    const float g0 = gamma[col0], g1 = gamma[col1];
    const float e0 = beta[col0],  e1 = beta[col1];
    #pragma unroll
    for (int mt = 0; mt < 4; ++mt) {
        #pragma unroll
        for (int r = 0; r < 4; ++r) {
            int row = mt * 16 + q * 4 + r;
            float tot  = red[row][0][0] + red[row][1][0] + red[row][2][0] + red[row][3][0];
            float tot2 = red[row][0][1] + red[row][1][1] + red[row][2][1] + red[row][3][1];
            float mu  = tot * (1.0f / HIDDEN);
            float var = tot2 * (1.0f / HIDDEN) - mu * mu;
            float rs  = rsqrtf(var + EPS);
            int node = base + row;
            if (node < N_NODES) {
                float v0 = fmaxf(g0 * (acc[mt][0][r] - mu) * rs + e0, 0.f);
                float v1 = fmaxf(g1 * (acc[mt][1][r] - mu) * rs + e1, 0.f);
                xout[(size_t)node * HIDDEN + col0] = __float2bfloat16(v0);
                xout[(size_t)node * HIDDEN + col1] = __float2bfloat16(v1);
                xoutf[(size_t)node * HIDDEN + col0] = f_to_fp8(v0);
                xoutf[(size_t)node * HIDDEN + col1] = f_to_fp8(v1);
            }
        }
    }
}

// layer-2 GEMM: mean-pool epilogue straight into pooled[] (batch sorted ->
// a 64-node block spans 1-2 graphs; 1 atomic/col/graph per block).
__global__ __launch_bounds__(256) void gemm_mfma_pool_kernel(
        const __hip_bfloat16* __restrict__ aggb, const __hip_bfloat16* __restrict__ xb,
        const int* __restrict__ batch, float* __restrict__ pooled,
        const __hip_bfloat16* __restrict__ Wt,
        const float* __restrict__ brel, const float* __restrict__ gamma,
        const float* __restrict__ beta) {
    __shared__ __align__(16) short sA[GM * 264];
    __shared__ float red[GM][4][2];
    __shared__ int sbatch[GM];

    const int tid  = threadIdx.x;
    const int w    = tid >> 6;
    const int lane = tid & 63;
    const int q    = lane >> 4;
    const int l15  = lane & 15;
    const int base = blockIdx.x * GM;

    if (tid < GM) {
        int node = base + tid;
        sbatch[tid] = (node < N_NODES) ? batch[node] : -1;
    }

    short8 breg[2][8];
    #pragma unroll
    for (int nt = 0; nt < 2; ++nt) {
        int col = 32 * w + nt * 16 + l15;
        const short* wp = (const short*)Wt + (size_t)col * 256;
        #pragma unroll
        for (int ks = 0; ks < 8; ++ks)
            breg[nt][ks] = *(const short8*)(wp + ks * 32 + q * 8);
    }

    for (int it = 0; it < 8; ++it) {
        int c = it * 256 + tid;
        int row = c >> 5, cc = c & 31;
        int node = base + row;
        short8 v = {0,0,0,0,0,0,0,0};
        if (node < N_NODES) {
            const short* gp = (cc < 16)
                ? (const short*)aggb + (size_t)node * HIDDEN + cc * 8
                : (const short*)xb   + (size_t)node * HIDDEN + (cc - 16) * 8;
            v = *(const short8*)gp;
        }
        *(short8*)&sA[row * 264 + cc * 8] = v;
    }
    __syncthreads();

    f32x4 acc[4][2];
    #pragma unroll
    for (int mt = 0; mt < 4; ++mt)
        #pragma unroll
        for (int nt = 0; nt < 2; ++nt)
            acc[mt][nt] = (f32x4){0.f, 0.f, 0.f, 0.f};

    #pragma unroll
    for (int ks = 0; ks < 8; ++ks) {
        short8 a[4];
        #pragma unroll
        for (int mt = 0; mt < 4; ++mt)
            a[mt] = *(short8*)&sA[(mt * 16 + l15) * 264 + ks * 32 + q * 8];
        #pragma unroll
        for (int mt = 0; mt < 4; ++mt) {
            acc[mt][0] = __builtin_amdgcn_mfma_f32_16x16x32_bf16(a[mt], breg[0][ks], acc[mt][0], 0, 0, 0);
            acc[mt][1] = __builtin_amdgcn_mfma_f32_16x16x32_bf16(a[mt], breg[1][ks], acc[mt][1], 0, 0, 0);
        }
    }

    const int col0 = 32 * w + l15, col1 = col0 + 16;
    const float b0 = brel[col0], b1 = brel[col1];
    #pragma unroll
    for (int mt = 0; mt < 4; ++mt) {
        #pragma unroll
        for (int r = 0; r < 4; ++r) {
            acc[mt][0][r] += b0;
            acc[mt][1][r] += b1;
            float s  = acc[mt][0][r] + acc[mt][1][r];
            float s2 = acc[mt][0][r] * acc[mt][0][r] + acc[mt][1][r] * acc[mt][1][r];
            #pragma unroll
            for (int off = 1; off < 16; off <<= 1) {
                s  += __shfl_xor(s,  off, 64);
                s2 += __shfl_xor(s2, off, 64);
            }
            if (l15 == 0) {
                red[mt * 16 + q * 4 + r][w][0] = s;
                red[mt * 16 + q * 4 + r][w][1] = s2;
            }
        }
    }
    __syncthreads();

    const float g0 = gamma[col0], g1 = gamma[col1];
    const float e0 = beta[col0],  e1 = beta[col1];
    #pragma unroll
    for (int mt = 0; mt < 4; ++mt) {
        #pragma unroll
        for (int r = 0; r < 4; ++r) {
            int row = mt * 16 + q * 4 + r;
            float tot  = red[row][0][0] + red[row][1][0] + red[row][2][0] + red[row][3][0];
            float tot2 = red[row][0][1] + red[row][1][1] + red[row][2][1] + red[row][3][1];
            float mu  = tot * (1.0f / HIDDEN);
            float var = tot2 * (1.0f / HIDDEN) - mu * mu;
            float rs  = rsqrtf(var + EPS);
            bool valid = (base + row) < N_NODES;
            float v0 = valid ? fmaxf(g0 * (acc[mt][0][r] - mu) * rs + e0, 0.f) : 0.f;
            float v1 = valid ? fmaxf(g1 * (acc[mt][1][r] - mu) * rs + e1, 0.f) : 0.f;
            acc[mt][0][r] = v0;
            acc[mt][1][r] = v1;
        }
    }

    int idxmax = N_NODES - 1 - base; if (idxmax > GM - 1) idxmax = GM - 1;
    const int gmin = sbatch[0], gmax = sbatch[idxmax];
    for (int g = gmin; g <= gmax; ++g) {
        float p0 = 0.f, p1 = 0.f;
        #pragma unroll
        for (int mt = 0; mt < 4; ++mt) {
            #pragma unroll
            for (int r = 0; r < 4; ++r) {
                int row = mt * 16 + q * 4 + r;
                if (sbatch[row] == g) { p0 += acc[mt][0][r]; p1 += acc[mt][1][r]; }
            }
        }
        p0 += __shfl_xor(p0, 16, 64); p0 += __shfl_xor(p0, 32, 64);
        p1 += __shfl_xor(p1, 16, 64); p1 += __shfl_xor(p1, 32, 64);
        if (q == 0) {
            atomicAdd(&pooled[g * HIDDEN + col0], p0);
            atomicAdd(&pooled[g * HIDDEN + col1], p1);
        }
    }
}

// head (derives per-graph counts from the sorted batch array)
__global__ void out_kernel(const float* __restrict__ pooled, const int* __restrict__ batch,
                           const float* __restrict__ Wc, const float* __restrict__ bc,
                           float* __restrict__ out) {
    int idx = blockIdx.x * blockDim.x + threadIdx.x;
    if (idx >= N_GRAPHS * OUT_F) return;
    int g = idx / OUT_F, o = idx % OUT_F;
    int lo = 0, hi = N_NODES;
    while (lo < hi) { int m = (lo + hi) >> 1; if (batch[m] < g) lo = m + 1; else hi = m; }
    int b0 = lo;
    lo = 0; hi = N_NODES;
    while (lo < hi) { int m = (lo + hi) >> 1; if (batch[m] < g + 1) lo = m + 1; else hi = m; }
    float cntf = (float)(lo - b0);
    float inv = 1.0f / fmaxf(cntf, 1.0f);
    float s = 0.f;
    for (int f = 0; f < HIDDEN; ++f)
        s += pooled[g * HIDDEN + f] * Wc[f * OUT_F + o];
    out[idx] = s * inv + bc[o];
}

// ---------------------------------------------------------------------------
static inline size_t align256(size_t v) { return (v + 255) & ~(size_t)255; }

extern "C" void kernel_launch(void* const* d_in, const int* in_sizes, int n_in,
                              void* d_out, int out_size, void* d_ws, size_t ws_size,
                              hipStream_t stream) {
    const float* x      = (const float*)d_in[0];
    const int*   eidx   = (const int*)d_in[1];
    const int*   batch  = (const int*)d_in[2];
    const float* W_rel  = (const float*)d_in[3];
    const float* b_rel  = (const float*)d_in[4];
    const float* W_root = (const float*)d_in[5];
    const float* gamma  = (const float*)d_in[6];
    const float* beta   = (const float*)d_in[7];
    const float* Wc     = (const float*)d_in[8];
    const float* bc     = (const float*)d_in[9];
    float* out = (float*)d_out;

    const int* src = eidx;
    const int* dst = eidx + N_EDGES;

    char* ws = (char*)d_ws;
    size_t off = 0;
    int*   row_ptr  = (int*)(ws + off);  off = align256(off + sizeof(int) * (N_NODES + 1));
    int*   csr_src  = (int*)(ws + off);  off = align256(off + sizeof(int) * N_EDGES);
    float* inv_deg  = (float*)(ws + off); off = align256(off + sizeof(float) * N_NODES);
    int*   cursor   = (int*)(ws + off);  off = align256(off + sizeof(int) * NB);
    int*   ebuf     = (int*)(ws + off);  off = align256(off + sizeof(int) * (size_t)NB * BCAP);
    __hip_bfloat16* x0b  = (__hip_bfloat16*)(ws + off); off = align256(off + 2 * (size_t)N_NODES * HIDDEN);
    __hip_bfloat16* x1b  = (__hip_bfloat16*)(ws + off); off = align256(off + 2 * (size_t)N_NODES * HIDDEN);
    __hip_bfloat16* aggb = (__hip_bfloat16*)(ws + off); off = align256(off + 2 * (size_t)N_NODES * HIDDEN);
    unsigned char* x0f = (unsigned char*)(ws + off); off = align256(off + (size_t)N_NODES * HIDDEN);
    unsigned char* x1f = (unsigned char*)(ws + off); off = align256(off + (size_t)N_NODES * HIDDEN);
    __hip_bfloat16* Wt   = (__hip_bfloat16*)(ws + off); off = align256(off + 2 * (size_t)2 * HIDDEN * 256);
    float* pooled   = (float*)(ws + off); off = align256(off + sizeof(float) * N_GRAPHS * HIDDEN);

    hipMemsetAsync(cursor, 0, sizeof(int) * NB, stream);

    // prep: edge partition + W cast + pooled zero + x cast (bf16 + fp8)
    prep_kernel<<<PREP_NB, 256, 0, stream>>>(
        x, x0b, x0f, W_rel, W_root, Wt, src, dst, cursor, ebuf, pooled);
    fillb_kernel<<<NB, 256, 0, stream>>>(cursor, ebuf, row_ptr, inv_deg, csr_src);

    const int agg_blocks  = (N_NODES * 64) / 256;      // 12500
    const int gemm_blocks = (N_NODES + GM - 1) / GM;   // 782

    // layer 0 (fp8 gather)
    agg_kernel<<<agg_blocks, 256, 0, stream>>>(x0f, row_ptr, csr_src, inv_deg, aggb);
    gemm_mfma_ln_kernel<<<gemm_blocks, 256, 0, stream>>>(
        aggb, x0b, x1b, x1f, Wt, b_rel, gamma, beta);
    // layer 1 (fp8 gather; pool fused into epilogue)
    agg_kernel<<<agg_blocks, 256, 0, stream>>>(x1f, row_ptr, csr_src, inv_deg, aggb);
    gemm_mfma_pool_kernel<<<gemm_blocks, 256, 0, stream>>>(
        aggb, x1b, batch, pooled, Wt + 2 * HIDDEN * 256 / 2,
        b_rel + HIDDEN, gamma + HIDDEN, beta + HIDDEN);

    // head
    out_kernel<<<(N_GRAPHS * OUT_F + 255) / 256, 256, 0, stream>>>(pooled, batch, Wc, bc, out);
}

// Round 11
// 211.033 us; speedup vs baseline: 1.6431x; 1.0261x over previous
//
#include <hip/hip_runtime.h>
#include <hip/hip_bf16.h>
#include <hip/hip_fp8.h>

#define N_NODES 50000
#define N_EDGES 800000
#define HIDDEN  128
#define OUT_F   10
#define N_GRAPHS 128
#define EPS 1e-5f

#define NB   391                    // ceil(50000/128) buckets of 128 nodes
#define BCAP 3072                   // bucket capacity (mean 2048)
#define SLICE (N_EDGES / 256)       // 3125 edges per partition block

// merged prep kernel block ranges (part first: it's the critical path)
#define CASTW_B0  256
#define POOLZ_B0  512
#define CASTX_B0  576
#define CASTX_NB  6250              // N_NODES*HIDDEN/4 float4s / 256
#define PREP_NB   (CASTX_B0 + CASTX_NB)

using short8 = __attribute__((ext_vector_type(8))) short;
using f32x4  = __attribute__((ext_vector_type(4))) float;

// ---------------------------------------------------------------------------
// fp8 helpers (OCP e4m3), HW cvt when available
__device__ __forceinline__ unsigned int f4_to_fp8x4(float a, float b, float c, float d) {
#if __has_builtin(__builtin_amdgcn_cvt_pk_fp8_f32)
    int v = 0;
    v = __builtin_amdgcn_cvt_pk_fp8_f32(a, b, v, false);
    v = __builtin_amdgcn_cvt_pk_fp8_f32(c, d, v, true);
    return (unsigned int)v;
#else
    __hip_fp8_e4m3 ha(a), hb(b), hc(c), hd(d);
    return (unsigned int)ha.__x | ((unsigned int)hb.__x << 8) |
           ((unsigned int)hc.__x << 16) | ((unsigned int)hd.__x << 24);
#endif
}
__device__ __forceinline__ unsigned char f_to_fp8(float a) {
#if __has_builtin(__builtin_amdgcn_cvt_pk_fp8_f32)
    return (unsigned char)(__builtin_amdgcn_cvt_pk_fp8_f32(a, a, 0, false) & 0xff);
#else
    __hip_fp8_e4m3 h(a); return h.__x;
#endif
}
__device__ __forceinline__ void fp8x4_to_f(unsigned int w, float o[4]) {
#if __has_builtin(__builtin_amdgcn_cvt_pk_f32_fp8)
    typedef float v2f __attribute__((ext_vector_type(2)));
    v2f lo = __builtin_amdgcn_cvt_pk_f32_fp8((int)w, false);
    v2f hi = __builtin_amdgcn_cvt_pk_f32_fp8((int)w, true);
    o[0] = lo.x; o[1] = lo.y; o[2] = hi.x; o[3] = hi.y;
#else
    #pragma unroll
    for (int t = 0; t < 4; ++t) {
        __hip_fp8_e4m3 h; h.__x = (unsigned char)((w >> (8 * t)) & 0xff);
        o[t] = (float)h;
    }
#endif
}
// 16 fp8 (uint4) -> 16 bf16 (two short8)
__device__ __forceinline__ void fp8x16_to_bf16(uint4 wv, short8* dst) {
    union { __hip_bfloat162 h[8]; short8 v[2]; } o;
    unsigned int ws[4] = {wv.x, wv.y, wv.z, wv.w};
    float f[4];
    #pragma unroll
    for (int d = 0; d < 4; ++d) {
        fp8x4_to_f(ws[d], f);
        o.h[2 * d + 0].x = __float2bfloat16(f[0]);
        o.h[2 * d + 0].y = __float2bfloat16(f[1]);
        o.h[2 * d + 1].x = __float2bfloat16(f[2]);
        o.h[2 * d + 1].y = __float2bfloat16(f[3]);
    }
    dst[0] = o.v[0];
    dst[1] = o.v[1];
}

// ---------------------------------------------------------------------------
// merged prep: edge bucket-partition + W cast (bf16) + pooled zero + x cast
// (fp8 only). cursor zeroed by memset beforehand.
__global__ __launch_bounds__(256) void prep_kernel(
        const float* __restrict__ x, unsigned char* __restrict__ x0f,
        const float* __restrict__ Wrel, const float* __restrict__ Wroot,
        __hip_bfloat16* __restrict__ Wt,
        const int* __restrict__ src, const int* __restrict__ dst,
        int* __restrict__ cursor, int* __restrict__ ebuf,
        float* __restrict__ pooled) {
    __shared__ int s_pk[SLICE];
    __shared__ unsigned short s_bk[SLICE];
    __shared__ int hist[NB], base[NB];
    const int b = blockIdx.x, tid = threadIdx.x;

    if (b < CASTW_B0) {
        const int e0 = b * SLICE;
        for (int i = tid; i < NB; i += 256) hist[i] = 0;
        __syncthreads();
        for (int i = tid; i < SLICE; i += 256) {
            int s = src[e0 + i], d = dst[e0 + i];
            int bk = d >> 7;
            s_pk[i] = s | ((d & 127) << 16);
            s_bk[i] = (unsigned short)bk;
            atomicAdd(&hist[bk], 1);
        }
        __syncthreads();
        for (int i = tid; i < NB; i += 256) {
            int h = hist[i];
            base[i] = h ? atomicAdd(&cursor[i], h) : 0;
            hist[i] = 0;
        }
        __syncthreads();
        for (int i = tid; i < SLICE; i += 256) {
            int bk = s_bk[i];
            int off = base[bk] + atomicAdd(&hist[bk], 1);
            if (off < BCAP) ebuf[bk * BCAP + off] = s_pk[i];
        }
    } else if (b < POOLZ_B0) {
        int idx = (b - CASTW_B0) * 256 + tid;        // 65536
        int l = idx >> 15;
        int rem = idx & 32767;
        int n = rem >> 8;
        int k = rem & 255;
        float v = (k < HIDDEN) ? Wrel[l * HIDDEN * HIDDEN + k * HIDDEN + n]
                               : Wroot[l * HIDDEN * HIDDEN + (k - HIDDEN) * HIDDEN + n];
        Wt[idx] = __float2bfloat16(v);
    } else if (b < CASTX_B0) {
        int i = (b - POOLZ_B0) * 256 + tid;          // 16384
        pooled[i] = 0.f;
    } else {
        int i = (b - CASTX_B0) * 256 + tid;          // float4 index, 1.6M
        float4 v = ((const float4*)x)[i];
        ((unsigned int*)x0f)[i] = f4_to_fp8x4(v.x, v.y, v.z, v.w);
    }
}

// per-bucket local counting sort -> deg/inv_deg/row_ptr + coalesced csr write.
__global__ __launch_bounds__(256) void fillb_kernel(
        const int* __restrict__ cursor, const int* __restrict__ ebuf,
        int* __restrict__ row_ptr, float* __restrict__ inv_deg,
        int* __restrict__ csr_src) {
    __shared__ int lcsr[BCAP];
    __shared__ int hist[128], lofs[128];
    __shared__ int wtot[2];
    __shared__ int sred[4];
    __shared__ int sbase;
    const int b = blockIdx.x;
    const int tid = threadIdx.x;

    int partial = 0;
    for (int i = tid; i < b; i += 256) partial += cursor[i];
    #pragma unroll
    for (int off = 1; off < 64; off <<= 1) partial += __shfl_xor(partial, off, 64);
    if ((tid & 63) == 0) sred[tid >> 6] = partial;
    if (tid < 128) hist[tid] = 0;
    __syncthreads();
    if (tid == 0) sbase = sred[0] + sred[1] + sred[2] + sred[3];
    __syncthreads();
    const int base = sbase;

    int cnt = cursor[b]; if (cnt > BCAP) cnt = BCAP;
    const int* eb = ebuf + b * BCAP;

    for (int i = tid; i < cnt; i += 256) atomicAdd(&hist[eb[i] >> 16], 1);
    __syncthreads();
    if (tid < 128) {
        int lane = tid & 63;
        int v = hist[tid];
        int inc = v;
        #pragma unroll
        for (int off = 1; off < 64; off <<= 1) {
            int t = __shfl_up(inc, off, 64);
            if (lane >= off) inc += t;
        }
        lofs[tid] = inc - v;
        if (lane == 63) wtot[tid >> 6] = inc;
    }
    __syncthreads();
    if (tid >= 64 && tid < 128) lofs[tid] += wtot[0];
    __syncthreads();
    if (tid < 128) {
        int node = b * 128 + tid;
        if (node < N_NODES) {
            row_ptr[node] = base + lofs[tid];
            int d = hist[tid];
            inv_deg[node] = (d > 0) ? (1.0f / (float)d) : 0.0f;
        }
        hist[tid] = lofs[tid];
    }
    if (b == 0 && tid == 0) row_ptr[N_NODES] = N_EDGES;
    __syncthreads();
    for (int i = tid; i < cnt; i += 256) {
        int pk = eb[i];
        int p = atomicAdd(&hist[pk >> 16], 1);
        lcsr[p] = pk & 0xFFFF;
    }
    __syncthreads();
    for (int i = tid; i < cnt; i += 256) csr_src[base + i] = lcsr[i];
}

// ---------------------------------------------------------------------------
// mean aggregation, fp8 in / fp32 accum / fp8 out. Wave per node, split 32/32:
// one dword/lane gather covers TWO edges; x4 unroll (proven R6 structure).
__global__ void agg_kernel(const unsigned char* __restrict__ xf8, const int* __restrict__ row_ptr,
                           const int* __restrict__ csr_src, const float* __restrict__ inv_deg,
                           unsigned char* __restrict__ aggf) {
    int gid = blockIdx.x * blockDim.x + threadIdx.x;
    int node = gid >> 6;
    int lane = threadIdx.x & 63;
    if (node >= N_NODES) return;
    const int half = lane >> 5;
    const int l32  = lane & 31;
    const int beg = row_ptr[node], end = row_ptr[node + 1];

    float a[4][4];
    #pragma unroll
    for (int u = 0; u < 4; ++u)
        #pragma unroll
        for (int k = 0; k < 4; ++k) a[u][k] = 0.f;

    for (int c = beg; c < end; c += 64) {
        int ei = c + lane;
        int sidx = (ei < end) ? csr_src[ei] : 0;
        int nedge = end - c; if (nedge > 64) nedge = 64;
        int npair = nedge >> 1;
        int j = 0;
        for (; j + 4 <= npair; j += 4) {
            #pragma unroll
            for (int u = 0; u < 4; ++u) {
                int sj = __shfl(sidx, 2 * (j + u) + half, 64);
                unsigned int wv = ((const unsigned int*)(xf8 + (size_t)sj * HIDDEN))[l32];
                float f[4];
                fp8x4_to_f(wv, f);
                a[u][0] += f[0]; a[u][1] += f[1]; a[u][2] += f[2]; a[u][3] += f[3];
            }
        }
        for (; j < npair; ++j) {
            int sj = __shfl(sidx, 2 * j + half, 64);
            unsigned int wv = ((const unsigned int*)(xf8 + (size_t)sj * HIDDEN))[l32];
            float f[4];
            fp8x4_to_f(wv, f);
            a[0][0] += f[0]; a[0][1] += f[1]; a[0][2] += f[2]; a[0][3] += f[3];
        }
        if (nedge & 1) {
            int sj = __shfl(sidx, nedge - 1, 64);
            if (half == 0) {
                unsigned int wv = ((const unsigned int*)(xf8 + (size_t)sj * HIDDEN))[l32];
                float f[4];
                fp8x4_to_f(wv, f);
                a[0][0] += f[0]; a[0][1] += f[1]; a[0][2] += f[2]; a[0][3] += f[3];
            }
        }
    }

    float s0 = a[0][0] + a[1][0] + a[2][0] + a[3][0];
    float s1 = a[0][1] + a[1][1] + a[2][1] + a[3][1];
    float s2 = a[0][2] + a[1][2] + a[2][2] + a[3][2];
    float s3 = a[0][3] + a[1][3] + a[2][3] + a[3][3];
    s0 += __shfl_xor(s0, 32, 64);
    s1 += __shfl_xor(s1, 32, 64);
    s2 += __shfl_xor(s2, 32, 64);
    s3 += __shfl_xor(s3, 32, 64);

    if (half == 0) {
        float w = inv_deg[node];
        ((unsigned int*)(aggf + (size_t)node * HIDDEN))[l32] =
            f4_to_fp8x4(s0 * w, s1 * w, s2 * w, s3 * w);
    }
}

// ---------------------------------------------------------------------------
#define GM 64

// layer-1 GEMM: A staged from fp8 (aggf | xf), converted to bf16 in LDS;
// writes fp8 xoutf only.
__global__ __launch_bounds__(256) void gemm_mfma_ln_kernel(
        const unsigned char* __restrict__ aggf, const unsigned char* __restrict__ xf,
        unsigned char* __restrict__ xoutf,
        const __hip_bfloat16* __restrict__ Wt,
        const float* __restrict__ brel, const float* __restrict__ gamma,
        const float* __restrict__ beta) {
    __shared__ __align__(16) short sA[GM * 264];
    __shared__ float red[GM][4][2];

    const int tid  = threadIdx.x;
    const int w    = tid >> 6;
    const int lane = tid & 63;
    const int q    = lane >> 4;
    const int l15  = lane & 15;
    const int base = blockIdx.x * GM;

    short8 breg[2][8];
    #pragma unroll
    for (int nt = 0; nt < 2; ++nt) {
        int col = 32 * w + nt * 16 + l15;
        const short* wp = (const short*)Wt + (size_t)col * 256;
        #pragma unroll
        for (int ks = 0; ks < 8; ++ks)
            breg[nt][ks] = *(const short8*)(wp + ks * 32 + q * 8);
    }

    // stage A: 64 rows x 16 chunks of 16 fp8 (k<128 agg, else x) -> bf16 LDS
    for (int it = 0; it < 4; ++it) {
        int c = it * 256 + tid;          // 1024 chunks
        int row = c >> 4, cc = c & 15;
        int node = base + row;
        uint4 wv = {0, 0, 0, 0};
        if (node < N_NODES) {
            const uint4* gp = (cc < 8)
                ? (const uint4*)(aggf + (size_t)node * HIDDEN) + cc
                : (const uint4*)(xf   + (size_t)node * HIDDEN) + (cc - 8);
            wv = *gp;
        }
        fp8x16_to_bf16(wv, (short8*)&sA[row * 264 + cc * 16]);
    }
    __syncthreads();

    f32x4 acc[4][2];
    #pragma unroll
    for (int mt = 0; mt < 4; ++mt)
        #pragma unroll
        for (int nt = 0; nt < 2; ++nt)
            acc[mt][nt] = (f32x4){0.f, 0.f, 0.f, 0.f};

    #pragma unroll
    for (int ks = 0; ks < 8; ++ks) {
        short8 a[4];
        #pragma unroll
        for (int mt = 0; mt < 4; ++mt)
            a[mt] = *(short8*)&sA[(mt * 16 + l15) * 264 + ks * 32 + q * 8];
        #pragma unroll
        for (int mt = 0; mt < 4; ++mt) {
            acc[mt][0] = __builtin_amdgcn_mfma_f32_16x16x32_bf16(a[mt], breg[0][ks], acc[mt][0], 0, 0, 0);
            acc[mt][1] = __builtin_amdgcn_mfma_f32_16x16x32_bf16(a[mt], breg[1][ks], acc[mt][1], 0, 0, 0);
        }
    }

    const int col0 = 32 * w + l15, col1 = col0 + 16;
    const float b0 = brel[col0], b1 = brel[col1];
    #pragma unroll
    for (int mt = 0; mt < 4; ++mt) {
        #pragma unroll
        for (int r = 0; r < 4; ++r) {
            acc[mt][0][r] += b0;
            acc[mt][1][r] += b1;
            float s  = acc[mt][0][r] + acc[mt][1][r];
            float s2 = acc[mt][0][r] * acc[mt][0][r] + acc[mt][1][r] * acc[mt][1][r];
            #pragma unroll
            for (int off = 1; off < 16; off <<= 1) {
                s  += __shfl_xor(s,  off, 64);
                s2 += __shfl_xor(s2, off, 64);
            }
            if (l15 == 0) {
                red[mt * 16 + q * 4 + r][w][0] = s;
                red[mt * 16 + q * 4 + r][w][1] = s2;
            }
        }
    }
    __syncthreads();

    const float g0 = gamma[col0], g1 = gamma[col1];
    const float e0 = beta[col0],  e1 = beta[col1];
    #pragma unroll
    for (int mt = 0; mt < 4; ++mt) {
        #pragma unroll
        for (int r = 0; r < 4; ++r) {
            int row = mt * 16 + q * 4 + r;
            float tot  = red[row][0][0] + red[row][1][0] + red[row][2][0] + red[row][3][0];
            float tot2 = red[row][0][1] + red[row][1][1] + red[row][2][1] + red[row][3][1];
            float mu  = tot * (1.0f / HIDDEN);
            float var = tot2 * (1.0f / HIDDEN) - mu * mu;
            float rs  = rsqrtf(var + EPS);
            int node = base + row;
            if (node < N_NODES) {
                float v0 = fmaxf(g0 * (acc[mt][0][r] - mu) * rs + e0, 0.f);
                float v1 = fmaxf(g1 * (acc[mt][1][r] - mu) * rs + e1, 0.f);
                xoutf[(size_t)node * HIDDEN + col0] = f_to_fp8(v0);
                xoutf[(size_t)node * HIDDEN + col1] = f_to_fp8(v1);
            }
        }
    }
}

// layer-2 GEMM: same fp8 staging; mean-pool epilogue into pooled[].
__global__ __launch_bounds__(256) void gemm_mfma_pool_kernel(
        const unsigned char* __restrict__ aggf, const unsigned char* __restrict__ xf,
        const int* __restrict__ batch, float* __restrict__ pooled,
        const __hip_bfloat16* __restrict__ Wt,
        const float* __restrict__ brel, const float* __restrict__ gamma,
        const float* __restrict__ beta) {
    __shared__ __align__(16) short sA[GM * 264];
    __shared__ float red[GM][4][2];
    __shared__ int sbatch[GM];

    const int tid  = threadIdx.x;
    const int w    = tid >> 6;
    const int lane = tid & 63;
    const int q    = lane >> 4;
    const int l15  = lane & 15;
    const int base = blockIdx.x * GM;

    if (tid < GM) {
        int node = base + tid;
        sbatch[tid] = (node < N_NODES) ? batch[node] : -1;
    }

    short8 breg[2][8];
    #pragma unroll
    for (int nt = 0; nt < 2; ++nt) {
        int col = 32 * w + nt * 16 + l15;
        const short* wp = (const short*)Wt + (size_t)col * 256;
        #pragma unroll
        for (int ks = 0; ks < 8; ++ks)
            breg[nt][ks] = *(const short8*)(wp + ks * 32 + q * 8);
    }

    for (int it = 0; it < 4; ++it) {
        int c = it * 256 + tid;
        int row = c >> 4, cc = c & 15;
        int node = base + row;
        uint4 wv = {0, 0, 0, 0};
        if (node < N_NODES) {
            const uint4* gp = (cc < 8)
                ? (const uint4*)(aggf + (size_t)node * HIDDEN) + cc
                : (const uint4*)(xf   + (size_t)node * HIDDEN) + (cc - 8);
            wv = *gp;
        }
        fp8x16_to_bf16(wv, (short8*)&sA[row * 264 + cc * 16]);
    }
    __syncthreads();

    f32x4 acc[4][2];
    #pragma unroll
    for (int mt = 0; mt < 4; ++mt)
        #pragma unroll
        for (int nt = 0; nt < 2; ++nt)
            acc[mt][nt] = (f32x4){0.f, 0.f, 0.f, 0.f};

    #pragma unroll
    for (int ks = 0; ks < 8; ++ks) {
        short8 a[4];
        #pragma unroll
        for (int mt = 0; mt < 4; ++mt)
            a[mt] = *(short8*)&sA[(mt * 16 + l15) * 264 + ks * 32 + q * 8];
        #pragma unroll
        for (int mt = 0; mt < 4; ++mt) {
            acc[mt][0] = __builtin_amdgcn_mfma_f32_16x16x32_bf16(a[mt], breg[0][ks], acc[mt][0], 0, 0, 0);
            acc[mt][1] = __builtin_amdgcn_mfma_f32_16x16x32_bf16(a[mt], breg[1][ks], acc[mt][1], 0, 0, 0);
        }
    }

    const int col0 = 32 * w + l15, col1 = col0 + 16;
    const float b0 = brel[col0], b1 = brel[col1];
    #pragma unroll
    for (int mt = 0; mt < 4; ++mt) {
        #pragma unroll
        for (int r = 0; r < 4; ++r) {
            acc[mt][0][r] += b0;
            acc[mt][1][r] += b1;
            float s  = acc[mt][0][r] + acc[mt][1][r];
            float s2 = acc[mt][0][r] * acc[mt][0][r] + acc[mt][1][r] * acc[mt][1][r];
            #pragma unroll
            for (int off = 1; off < 16; off <<= 1) {
                s  += __shfl_xor(s,  off, 64);
                s2 += __shfl_xor(s2, off, 64);
            }
            if (l15 == 0) {
                red[mt * 16 + q * 4 + r][w][0] = s;
                red[mt * 16 + q * 4 + r][w][1] = s2;
            }
        }
    }
    __syncthreads();

    const float g0 = gamma[col0], g1 = gamma[col1];
    const float e0 = beta[col0],  e1 = beta[col1];
    #pragma unroll
    for (int mt = 0; mt < 4; ++mt) {
        #pragma unroll
        for (int r = 0; r < 4; ++r) {
            int row = mt * 16 + q * 4 + r;
            float tot  = red[row][0][0] + red[row][1][0] + red[row][2][0] + red[row][3][0];
            float tot2 = red[row][0][1] + red[row][1][1] + red[row][2][1] + red[row][3][1];
            float mu  = tot * (1.0f / HIDDEN);
            float var = tot2 * (1.0f / HIDDEN) - mu * mu;
            float rs  = rsqrtf(var + EPS);
            bool valid = (base + row) < N_NODES;
            float v0 = valid ? fmaxf(g0 * (acc[mt][0][r] - mu) * rs + e0, 0.f) : 0.f;
            float v1 = valid ? fmaxf(g1 * (acc[mt][1][r] - mu) * rs + e1, 0.f) : 0.f;
            acc[mt][0][r] = v0;
            acc[mt][1][r] = v1;
        }
    }

    int idxmax = N_NODES - 1 - base; if (idxmax > GM - 1) idxmax = GM - 1;
    const int gmin = sbatch[0], gmax = sbatch[idxmax];
    for (int g = gmin; g <= gmax; ++g) {
        float p0 = 0.f, p1 = 0.f;
        #pragma unroll
        for (int mt = 0; mt < 4; ++mt) {
            #pragma unroll
            for (int r = 0; r < 4; ++r) {
                int row = mt * 16 + q * 4 + r;
                if (sbatch[row] == g) { p0 += acc[mt][0][r]; p1 += acc[mt][1][r]; }
            }
        }
        p0 += __shfl_xor(p0, 16, 64); p0 += __shfl_xor(p0, 32, 64);
        p1 += __shfl_xor(p1, 16, 64); p1 += __shfl_xor(p1, 32, 64);
        if (q == 0) {
            atomicAdd(&pooled[g * HIDDEN + col0], p0);
            atomicAdd(&pooled[g * HIDDEN + col1], p1);
        }
    }
}

// head (derives per-graph counts from the sorted batch array)
__global__ void out_kernel(const float* __restrict__ pooled, const int* __restrict__ batch,
                           const float* __restrict__ Wc, const float* __restrict__ bc,
                           float* __restrict__ out) {
    int idx = blockIdx.x * blockDim.x + threadIdx.x;
    if (idx >= N_GRAPHS * OUT_F) return;
    int g = idx / OUT_F, o = idx % OUT_F;
    int lo = 0, hi = N_NODES;
    while (lo < hi) { int m = (lo + hi) >> 1; if (batch[m] < g) lo = m + 1; else hi = m; }
    int b0 = lo;
    lo = 0; hi = N_NODES;
    while (lo < hi) { int m = (lo + hi) >> 1; if (batch[m] < g + 1) lo = m + 1; else hi = m; }
    float cntf = (float)(lo - b0);
    float inv = 1.0f / fmaxf(cntf, 1.0f);
    float s = 0.f;
    for (int f = 0; f < HIDDEN; ++f)
        s += pooled[g * HIDDEN + f] * Wc[f * OUT_F + o];
    out[idx] = s * inv + bc[o];
}

// ---------------------------------------------------------------------------
static inline size_t align256(size_t v) { return (v + 255) & ~(size_t)255; }

extern "C" void kernel_launch(void* const* d_in, const int* in_sizes, int n_in,
                              void* d_out, int out_size, void* d_ws, size_t ws_size,
                              hipStream_t stream) {
    const float* x      = (const float*)d_in[0];
    const int*   eidx   = (const int*)d_in[1];
    const int*   batch  = (const int*)d_in[2];
    const float* W_rel  = (const float*)d_in[3];
    const float* b_rel  = (const float*)d_in[4];
    const float* W_root = (const float*)d_in[5];
    const float* gamma  = (const float*)d_in[6];
    const float* beta   = (const float*)d_in[7];
    const float* Wc     = (const float*)d_in[8];
    const float* bc     = (const float*)d_in[9];
    float* out = (float*)d_out;

    const int* src = eidx;
    const int* dst = eidx + N_EDGES;

    char* ws = (char*)d_ws;
    size_t off = 0;
    int*   row_ptr  = (int*)(ws + off);  off = align256(off + sizeof(int) * (N_NODES + 1));
    int*   csr_src  = (int*)(ws + off);  off = align256(off + sizeof(int) * N_EDGES);
    float* inv_deg  = (float*)(ws + off); off = align256(off + sizeof(float) * N_NODES);
    int*   cursor   = (int*)(ws + off);  off = align256(off + sizeof(int) * NB);
    int*   ebuf     = (int*)(ws + off);  off = align256(off + sizeof(int) * (size_t)NB * BCAP);
    unsigned char* x0f  = (unsigned char*)(ws + off); off = align256(off + (size_t)N_NODES * HIDDEN);
    unsigned char* x1f  = (unsigned char*)(ws + off); off = align256(off + (size_t)N_NODES * HIDDEN);
    unsigned char* aggf = (unsigned char*)(ws + off); off = align256(off + (size_t)N_NODES * HIDDEN);
    __hip_bfloat16* Wt  = (__hip_bfloat16*)(ws + off); off = align256(off + 2 * (size_t)2 * HIDDEN * 256);
    float* pooled   = (float*)(ws + off); off = align256(off + sizeof(float) * N_GRAPHS * HIDDEN);

    hipMemsetAsync(cursor, 0, sizeof(int) * NB, stream);

    // prep: edge partition + W cast + pooled zero + x cast (fp8)
    prep_kernel<<<PREP_NB, 256, 0, stream>>>(
        x, x0f, W_rel, W_root, Wt, src, dst, cursor, ebuf, pooled);
    fillb_kernel<<<NB, 256, 0, stream>>>(cursor, ebuf, row_ptr, inv_deg, csr_src);

    const int agg_blocks  = (N_NODES * 64) / 256;      // 12500
    const int gemm_blocks = (N_NODES + GM - 1) / GM;   // 782

    // layer 0
    agg_kernel<<<agg_blocks, 256, 0, stream>>>(x0f, row_ptr, csr_src, inv_deg, aggf);
    gemm_mfma_ln_kernel<<<gemm_blocks, 256, 0, stream>>>(
        aggf, x0f, x1f, Wt, b_rel, gamma, beta);
    // layer 1 (pool fused into epilogue)
    agg_kernel<<<agg_blocks, 256, 0, stream>>>(x1f, row_ptr, csr_src, inv_deg, aggf);
    gemm_mfma_pool_kernel<<<gemm_blocks, 256, 0, stream>>>(
        aggf, x1f, batch, pooled, Wt + 2 * HIDDEN * 256 / 2,
        b_rel + HIDDEN, gamma + HIDDEN, beta + HIDDEN);

    // head
    out_kernel<<<(N_GRAPHS * OUT_F + 255) / 256, 256, 0, stream>>>(pooled, batch, Wc, bc, out);
}